// Round 1
// baseline (896.309 us; speedup 1.0000x reference)
//
#include <hip/hip_runtime.h>
#include <math.h>

// GATLayer fused baseline (fp32). B=4, N=2048, Din=Dout=768.
// Pipeline: K1 gemm (Wh0,Wh1) -> K2 svec (8 projections) -> K3 score+column stats
//           -> K4 combine stats -> K5 A@Wh1 with on-the-fly softmax + elu.

#define B 4
#define N 2048
#define D 768
#define BN_TOT (B * N)          // 8192
#define NSPLIT 16               // i-splits for column stats
#define ISPAN (N / NSPLIT)      // 128

constexpr float ALPHA = 0.2f;   // leaky slope
constexpr float SCALE = 0.01f;

__device__ __forceinline__ float leaky(float x) {
    return x > 0.f ? x : ALPHA * x;
}

// ---------------------------------------------------------------------------
// K1: Wh = h @ W  (fp32 tiled SGEMM, 128x128 tile, BK=8, 256 thr, 8x8/thread)
// grid (D/128, BN_TOT/128, 2)  z: 0 -> h0, 1 -> h1
// ---------------------------------------------------------------------------
__global__ __launch_bounds__(256) void gemm_wh(
    const float* __restrict__ h0, const float* __restrict__ h1,
    const float* __restrict__ W,
    float* __restrict__ Wh0, float* __restrict__ Wh1) {
    __shared__ float As[8][128];
    __shared__ float Bs[8][128];
    const float* src = blockIdx.z ? h1 : h0;
    float* dst = blockIdx.z ? Wh1 : Wh0;
    const int row0 = blockIdx.y * 128;
    const int col0 = blockIdx.x * 128;
    const int tid = threadIdx.x;
    const int ty = tid / 16, tx = tid % 16;   // 16x16 threads, 8x8 each
    const int ar = tid / 2;                   // A row 0..127
    const int ak = (tid % 2) * 4;             // A k sub-offset 0/4
    const int bk = tid / 32;                  // B k row 0..7
    const int bc = (tid % 32) * 4;            // B col 0..124
    float acc[8][8] = {};

    for (int k0 = 0; k0 < D; k0 += 8) {
        const float4 av = *(const float4*)&src[(size_t)(row0 + ar) * D + k0 + ak];
        As[ak + 0][ar] = av.x; As[ak + 1][ar] = av.y;
        As[ak + 2][ar] = av.z; As[ak + 3][ar] = av.w;
        *(float4*)&Bs[bk][bc] = *(const float4*)&W[(size_t)(k0 + bk) * D + col0 + bc];
        __syncthreads();
        #pragma unroll
        for (int kk = 0; kk < 8; ++kk) {
            float rm[8], rn[8];
            #pragma unroll
            for (int e = 0; e < 8; ++e) rm[e] = As[kk][ty * 8 + e];
            #pragma unroll
            for (int e = 0; e < 8; ++e) rn[e] = Bs[kk][tx * 8 + e];
            #pragma unroll
            for (int i = 0; i < 8; ++i)
                #pragma unroll
                for (int j = 0; j < 8; ++j)
                    acc[i][j] = fmaf(rm[i], rn[j], acc[i][j]);
        }
        __syncthreads();
    }
    #pragma unroll
    for (int i = 0; i < 8; ++i) {
        size_t o = (size_t)(row0 + ty * 8 + i) * D + col0 + tx * 8;
        *(float4*)&dst[o]     = make_float4(acc[i][0], acc[i][1], acc[i][2], acc[i][3]);
        *(float4*)&dst[o + 4] = make_float4(acc[i][4], acc[i][5], acc[i][6], acc[i][7]);
    }
}

// ---------------------------------------------------------------------------
// K2: 8 scalar projections. svec[v][b*N+row]:
//  v0 = Wh0 . a[:D]    v1 = Wh1 . a[D:]
//  v2 = Wh0 . n1[:D]   v3 = Wh1 . n1[D:]
//  v4 = Wh0 . n2[:D]   v5 = Wh1 . n2[D:]
//  v6 = Wh0 . n3[:D]   v7 = Wh1 . n3[D:]
// one wave per row; grid BN_TOT/4, block 256
// ---------------------------------------------------------------------------
__global__ __launch_bounds__(256) void svec_kernel(
    const float* __restrict__ Wh0, const float* __restrict__ Wh1,
    const float* __restrict__ a,  const float* __restrict__ n1,
    const float* __restrict__ n2, const float* __restrict__ n3,
    float* __restrict__ svec) {
    const int wave = threadIdx.x >> 6;
    const int lane = threadIdx.x & 63;
    const int row = blockIdx.x * 4 + wave;
    float s[8] = {0.f, 0.f, 0.f, 0.f, 0.f, 0.f, 0.f, 0.f};
    #pragma unroll
    for (int t = 0; t < D / 64; ++t) {
        const int k = lane + t * 64;
        const float w0 = Wh0[(size_t)row * D + k];
        const float w1 = Wh1[(size_t)row * D + k];
        s[0] = fmaf(w0, a[k],      s[0]);  s[1] = fmaf(w1, a[D + k],  s[1]);
        s[2] = fmaf(w0, n1[k],     s[2]);  s[3] = fmaf(w1, n1[D + k], s[3]);
        s[4] = fmaf(w0, n2[k],     s[4]);  s[5] = fmaf(w1, n2[D + k], s[5]);
        s[6] = fmaf(w0, n3[k],     s[6]);  s[7] = fmaf(w1, n3[D + k], s[7]);
    }
    #pragma unroll
    for (int v = 0; v < 8; ++v) {
        float x = s[v];
        #pragma unroll
        for (int off = 32; off; off >>= 1) x += __shfl_xor(x, off);
        if (lane == 0) svec[v * BN_TOT + row] = x;
    }
}

// ---------------------------------------------------------------------------
// K3: score[b,i,j] + per-(b,j) partial online max/sumexp over an i-span.
// grid (N/256, NSPLIT, B), block 256 (one thread per column j)
// ---------------------------------------------------------------------------
__global__ __launch_bounds__(256) void colstat_kernel(
    const int* __restrict__ e1, const int* __restrict__ e2,
    const int* __restrict__ e3, const float* __restrict__ svec,
    float* __restrict__ score, float* __restrict__ pm, float* __restrict__ pl) {
    const int b = blockIdx.z;
    const int i0 = blockIdx.y * ISPAN;
    const int j = blockIdx.x * 256 + threadIdx.x;
    const int bn = b * N;
    const float va = svec[1 * BN_TOT + bn + j];
    const float v1 = svec[3 * BN_TOT + bn + j];
    const float v2 = svec[5 * BN_TOT + bn + j];
    const float v3 = svec[7 * BN_TOT + bn + j];
    float m = -1e30f, l = 0.f;
    #pragma unroll 4
    for (int i = i0; i < i0 + ISPAN; ++i) {
        const float ua = svec[0 * BN_TOT + bn + i];
        const float u1 = svec[2 * BN_TOT + bn + i];
        const float u2 = svec[4 * BN_TOT + bn + i];
        const float u3 = svec[6 * BN_TOT + bn + i];
        const size_t eoff = (size_t)(bn + i) * N + j;
        float s = leaky(ua + va);
        float acc = 0.f;
        acc += (e1[eoff] > 0) ? leaky(u1 + v1) : 0.f;
        acc += (e2[eoff] > 0) ? leaky(u2 + v2) : 0.f;
        acc += (e3[eoff] > 0) ? leaky(u3 + v3) : 0.f;
        s = fmaf(SCALE, acc, s);
        score[eoff] = s;
        const float mn = fmaxf(m, s);
        l = l * __expf(m - mn) + __expf(s - mn);
        m = mn;
    }
    const size_t po = (size_t)(b * NSPLIT + blockIdx.y) * N + j;
    pm[po] = m;
    pl[po] = l;
}

// ---------------------------------------------------------------------------
// K4: combine NSPLIT partials -> cst[b*N+j] = m* + log(l*)
// attention = exp(score - cst)
// ---------------------------------------------------------------------------
__global__ __launch_bounds__(256) void combine_kernel(
    const float* __restrict__ pm, const float* __restrict__ pl,
    float* __restrict__ cst) {
    const int idx = blockIdx.x * 256 + threadIdx.x;   // b*N + j
    const int b = idx / N, j = idx % N;
    float m = -1e30f;
    #pragma unroll
    for (int s = 0; s < NSPLIT; ++s)
        m = fmaxf(m, pm[(size_t)(b * NSPLIT + s) * N + j]);
    float l = 0.f;
    #pragma unroll
    for (int s = 0; s < NSPLIT; ++s) {
        const size_t o = (size_t)(b * NSPLIT + s) * N + j;
        l += pl[o] * __expf(pm[o] - m);
    }
    cst[idx] = m + logf(l);
}

// ---------------------------------------------------------------------------
// K5: out = elu( softmax_col(S) @ Wh1 ).  A built on the fly: exp(S - cst[j]).
// 128x128 tile over (i,d), K = j = 2048, BK=16, 512 thr, 8x4 per thread.
// grid (D/128, N/128, B)
// ---------------------------------------------------------------------------
__global__ __launch_bounds__(512) void av_kernel(
    const float* __restrict__ score, const float* __restrict__ Wh1,
    const float* __restrict__ cst, float* __restrict__ out) {
    __shared__ float As[16][128];
    __shared__ float Bs[16][128];
    __shared__ float cs[N];                 // 8 KB: cst row for this b
    const int b = blockIdx.z;
    const int i0 = blockIdx.y * 128;
    const int d0 = blockIdx.x * 128;
    const int tid = threadIdx.x;
    for (int t = tid; t < N; t += 512) cs[t] = cst[b * N + t];
    __syncthreads();

    const int ty = tid / 32, tx = tid % 32; // 8 rows x 4 cols per thread
    const int ar = tid / 4;                 // A row (i) 0..127
    const int ac = (tid % 4) * 4;           // A k sub-offset 0..12
    const int br = tid / 32;                // B k row 0..15
    const int bc = (tid % 32) * 4;          // B col (d) 0..124
    float acc[8][4] = {};

    for (int k0 = 0; k0 < N; k0 += 16) {
        const float4 sv = *(const float4*)&score[(size_t)(b * N + i0 + ar) * N + k0 + ac];
        As[ac + 0][ar] = __expf(sv.x - cs[k0 + ac + 0]);
        As[ac + 1][ar] = __expf(sv.y - cs[k0 + ac + 1]);
        As[ac + 2][ar] = __expf(sv.z - cs[k0 + ac + 2]);
        As[ac + 3][ar] = __expf(sv.w - cs[k0 + ac + 3]);
        *(float4*)&Bs[br][bc] =
            *(const float4*)&Wh1[(size_t)(b * N + k0 + br) * D + d0 + bc];
        __syncthreads();
        #pragma unroll
        for (int kk = 0; kk < 16; ++kk) {
            float rm[8], rn[4];
            #pragma unroll
            for (int e = 0; e < 8; ++e) rm[e] = As[kk][ty * 8 + e];
            #pragma unroll
            for (int e = 0; e < 4; ++e) rn[e] = Bs[kk][tx * 4 + e];
            #pragma unroll
            for (int i = 0; i < 8; ++i)
                #pragma unroll
                for (int j = 0; j < 4; ++j)
                    acc[i][j] = fmaf(rm[i], rn[j], acc[i][j]);
        }
        __syncthreads();
    }
    #pragma unroll
    for (int i = 0; i < 8; ++i) {
        float4 o;
        o.x = acc[i][0] > 0.f ? acc[i][0] : expm1f(acc[i][0]);
        o.y = acc[i][1] > 0.f ? acc[i][1] : expm1f(acc[i][1]);
        o.z = acc[i][2] > 0.f ? acc[i][2] : expm1f(acc[i][2]);
        o.w = acc[i][3] > 0.f ? acc[i][3] : expm1f(acc[i][3]);
        *(float4*)&out[(size_t)(b * N + i0 + ty * 8 + i) * D + d0 + tx * 4] = o;
    }
}

// ---------------------------------------------------------------------------
extern "C" void kernel_launch(void* const* d_in, const int* in_sizes, int n_in,
                              void* d_out, int out_size, void* d_ws, size_t ws_size,
                              hipStream_t stream) {
    const float* h0  = (const float*)d_in[0];
    const float* h1  = (const float*)d_in[1];
    const float* nl1 = (const float*)d_in[2];
    const int*   e1  = (const int*)d_in[3];
    const float* nl2 = (const float*)d_in[4];
    const int*   e2  = (const int*)d_in[5];
    const float* nl3 = (const float*)d_in[6];
    const int*   e3  = (const int*)d_in[7];
    const float* W   = (const float*)d_in[8];
    const float* a   = (const float*)d_in[9];
    float* out = (float*)d_out;

    // workspace layout (floats): 119 MB total
    float* ws    = (float*)d_ws;
    float* Wh0   = ws;                                  // B*N*D
    float* Wh1   = Wh0 + (size_t)BN_TOT * D;            // B*N*D
    float* score = Wh1 + (size_t)BN_TOT * D;            // B*N*N
    float* svec  = score + (size_t)BN_TOT * N;          // 8*B*N
    float* pm    = svec + (size_t)8 * BN_TOT;           // NSPLIT*B*N
    float* pl    = pm + (size_t)NSPLIT * BN_TOT;        // NSPLIT*B*N
    float* cst   = pl + (size_t)NSPLIT * BN_TOT;        // B*N

    gemm_wh<<<dim3(D / 128, BN_TOT / 128, 2), 256, 0, stream>>>(h0, h1, W, Wh0, Wh1);
    svec_kernel<<<BN_TOT / 4, 256, 0, stream>>>(Wh0, Wh1, a, nl1, nl2, nl3, svec);
    colstat_kernel<<<dim3(N / 256, NSPLIT, B), 256, 0, stream>>>(e1, e2, e3, svec,
                                                                 score, pm, pl);
    combine_kernel<<<BN_TOT / 256, 256, 0, stream>>>(pm, pl, cst);
    av_kernel<<<dim3(D / 128, N / 128, B), 512, 0, stream>>>(score, Wh1, cst, out);
}

// Round 4
// 464.265 us; speedup vs baseline: 1.9306x; 1.9306x over previous
//
#include <hip/hip_runtime.h>
#include <math.h>

// GATLayer fused, round 4 (= round-2 kernel, resubmitted after 2x broker timeout):
// both GEMMs on bf16 MFMA with 3-term split precision.
// Pipeline: split_h, split_wt -> gemm_wh_mfma (Wh fp32 + Vt split-bf16)
//           -> svec -> colstat (score fp32 + col stats) -> combine
//           -> abuild (score -> attention split-bf16, in place) -> av_mfma (+elu)

#define B 4
#define N 2048
#define D 768
#define BN_TOT (B * N)          // 8192
#define NSPLIT 16
#define ISPAN (N / NSPLIT)      // 128

constexpr float ALPHA = 0.2f;
constexpr float SCALE = 0.01f;

typedef __attribute__((ext_vector_type(8))) short bf16x8;   // 8 bf16 = 4 VGPR
typedef __attribute__((ext_vector_type(4))) short short4v;
typedef __attribute__((ext_vector_type(4))) float f32x4;

__device__ __forceinline__ float leaky(float x) { return x > 0.f ? x : ALPHA * x; }

// fp32 -> bf16 hi + bf16 lo (truncation; r = x - hi is exact, combined ~16-bit mantissa)
__device__ __forceinline__ void split2(float x, short& h, short& l) {
    unsigned bx = __float_as_uint(x);
    h = (short)(bx >> 16);
    float r = x - __uint_as_float(bx & 0xffff0000u);
    l = (short)(__float_as_uint(r) >> 16);
}

__device__ __forceinline__ void gload16(const void* g, void* l) {
    __builtin_amdgcn_global_load_lds(
        (const __attribute__((address_space(1))) void*)g,
        (__attribute__((address_space(3))) void*)l, 16, 0, 0);
}

// ---------------------------------------------------------------------------
// split32 format: fp32 array [R][C] -> per 8 elems: 16B hi-bf16x8 then 16B lo.
// Row stride (bytes) = C*4, chunk c (k-range [8c,8c+8)) at byte c*32 (+16 lo).
// ---------------------------------------------------------------------------

// h0,h1 -> split32. grid (3072, 2) x 256
__global__ __launch_bounds__(256) void split_h_kernel(
    const float* __restrict__ h0, const float* __restrict__ h1,
    char* __restrict__ hs0, char* __restrict__ hs1) {
    const size_t cidx = (size_t)blockIdx.x * 256 + threadIdx.x;   // 786432 chunks
    const float* src = blockIdx.y ? h1 : h0;
    char* dst = blockIdx.y ? hs1 : hs0;
    float v[8];
    *(float4*)&v[0] = *(const float4*)&src[cidx * 8];
    *(float4*)&v[4] = *(const float4*)&src[cidx * 8 + 4];
    short h[8], l[8];
    #pragma unroll
    for (int e = 0; e < 8; ++e) split2(v[e], h[e], l[e]);
    *(bf16x8*)(dst + cidx * 32) = bf16x8{h[0],h[1],h[2],h[3],h[4],h[5],h[6],h[7]};
    *(bf16x8*)(dst + cidx * 32 + 16) = bf16x8{l[0],l[1],l[2],l[3],l[4],l[5],l[6],l[7]};
}

// W[k][n] -> Wts[n][k] split32 (transposed). grid 288 x 256
__global__ __launch_bounds__(256) void split_wt_kernel(
    const float* __restrict__ W, char* __restrict__ Wts) {
    const int cidx = blockIdx.x * 256 + threadIdx.x;   // 768*96 = 73728
    const int n = cidx / (D / 8);
    const int k0 = (cidx % (D / 8)) * 8;
    short h[8], l[8];
    #pragma unroll
    for (int e = 0; e < 8; ++e) split2(W[(size_t)(k0 + e) * D + n], h[e], l[e]);
    *(bf16x8*)(Wts + (size_t)cidx * 32) = bf16x8{h[0],h[1],h[2],h[3],h[4],h[5],h[6],h[7]};
    *(bf16x8*)(Wts + (size_t)cidx * 32 + 16) = bf16x8{l[0],l[1],l[2],l[3],l[4],l[5],l[6],l[7]};
}

// ---------------------------------------------------------------------------
// Shared MFMA core: 128x128 tile, BK=64, 4 waves (2x2), 64x64 per wave,
// 16x16x32 bf16 MFMA, 3-term split accumulate. LDS 4x16KB linear tiles,
// XOR-swizzled (chunk ^= row&7) on both stage-source and ds_read (rule #21).
// ---------------------------------------------------------------------------
__device__ __forceinline__ void mfma_core(
    const char* Asrc, size_t Astride, const char* Bsrc, size_t Bstride,
    int ksteps, short* lds, f32x4 (&acc)[4][4], int wid, int lane) {
    short* Ah = lds;
    short* Al = lds + 8192;
    short* Bh = lds + 16384;
    short* Bl = lds + 24576;
    const int wr = wid >> 1, wc = wid & 1;
    const int lrow = lane & 15, kg = lane >> 4;

    for (int kt = 0; kt < ksteps; ++kt) {
        __syncthreads();   // prev compute done reading LDS
        #pragma unroll
        for (int s = 0; s < 4; ++s) {
            const int seg = s * 4 + wid;              // 16 x 1KB segments per tile
            const int row = seg * 8 + (lane >> 3);    // 0..127
            const int c = (lane & 7) ^ (row & 7);     // pre-swizzled source chunk
            const char* ga = Asrc + (size_t)kt * 256 + (size_t)row * Astride + c * 32;
            gload16(ga,      (char*)Ah + seg * 1024);
            gload16(ga + 16, (char*)Al + seg * 1024);
            const char* gb = Bsrc + (size_t)kt * 256 + (size_t)row * Bstride + c * 32;
            gload16(gb,      (char*)Bh + seg * 1024);
            gload16(gb + 16, (char*)Bl + seg * 1024);
        }
        __syncthreads();   // vmcnt(0): tiles ready
        #pragma unroll
        for (int ks = 0; ks < 2; ++ks) {
            bf16x8 ah[4], al[4], bh[4], bl[4];
            #pragma unroll
            for (int m = 0; m < 4; ++m) {
                const int r = wr * 64 + m * 16 + lrow;
                const int c = (ks * 4 + kg) ^ (r & 7);
                ah[m] = *(const bf16x8*)((const char*)Ah + r * 128 + c * 16);
                al[m] = *(const bf16x8*)((const char*)Al + r * 128 + c * 16);
            }
            #pragma unroll
            for (int n = 0; n < 4; ++n) {
                const int r = wc * 64 + n * 16 + lrow;
                const int c = (ks * 4 + kg) ^ (r & 7);
                bh[n] = *(const bf16x8*)((const char*)Bh + r * 128 + c * 16);
                bl[n] = *(const bf16x8*)((const char*)Bl + r * 128 + c * 16);
            }
            #pragma unroll
            for (int m = 0; m < 4; ++m)
                #pragma unroll
                for (int n = 0; n < 4; ++n) {
                    acc[m][n] = __builtin_amdgcn_mfma_f32_16x16x32_bf16(ah[m], bh[n], acc[m][n], 0, 0, 0);
                    acc[m][n] = __builtin_amdgcn_mfma_f32_16x16x32_bf16(ah[m], bl[n], acc[m][n], 0, 0, 0);
                    acc[m][n] = __builtin_amdgcn_mfma_f32_16x16x32_bf16(al[m], bh[n], acc[m][n], 0, 0, 0);
                }
        }
    }
}

// K1: Wh = h @ W. grid (6, 64, 2) x 256. Writes Wh fp32; z==1 also Vt split32.
__global__ __launch_bounds__(256, 2) void gemm_wh_mfma(
    const char* __restrict__ hs0, const char* __restrict__ hs1,
    const char* __restrict__ Wts,
    float* __restrict__ Wh0, float* __restrict__ Wh1, char* __restrict__ Vts) {
    __shared__ short lds[4 * 8192];
    const int tid = threadIdx.x, wid = tid >> 6, lane = tid & 63;
    const int z = blockIdx.z;
    const int row0 = blockIdx.y * 128, col0 = blockIdx.x * 128;
    const char* Asrc = (z ? hs1 : hs0) + (size_t)row0 * 3072;   // h rows, 768*4B
    const char* Bsrc = Wts + (size_t)col0 * 3072;               // Wt rows = out cols
    f32x4 acc[4][4] = {};
    mfma_core(Asrc, 3072, Bsrc, 3072, D / 64, lds, acc, wid, lane);

    float* dst = z ? Wh1 : Wh0;
    const int wr = wid >> 1, wc = wid & 1;
    const int lrow = lane & 15, kg = lane >> 4;
    #pragma unroll
    for (int m = 0; m < 4; ++m)
        #pragma unroll
        for (int n = 0; n < 4; ++n) {
            const int rowb = row0 + wr * 64 + m * 16 + kg * 4;   // C/D: col=lane&15,
            const int col = col0 + wc * 64 + n * 16 + lrow;      // row=(lane>>4)*4+r
            #pragma unroll
            for (int r = 0; r < 4; ++r)
                dst[(size_t)(rowb + r) * D + col] = acc[m][n][r];
            if (z) {   // Vt[b][d][j] split32: contiguous in j == acc reg index
                const int b = rowb >> 11, j = rowb & (N - 1);
                short h4[4], l4[4];
                #pragma unroll
                for (int r = 0; r < 4; ++r) split2(acc[m][n][r], h4[r], l4[r]);
                char* base = Vts + ((size_t)(b * D + col)) * 8192 + (j >> 3) * 32 + (j & 7) * 2;
                *(short4v*)base        = short4v{h4[0], h4[1], h4[2], h4[3]};
                *(short4v*)(base + 16) = short4v{l4[0], l4[1], l4[2], l4[3]};
            }
        }
}

// K2: 8 scalar projections (fp32)
__global__ __launch_bounds__(256) void svec_kernel(
    const float* __restrict__ Wh0, const float* __restrict__ Wh1,
    const float* __restrict__ a,  const float* __restrict__ n1,
    const float* __restrict__ n2, const float* __restrict__ n3,
    float* __restrict__ svec) {
    const int wave = threadIdx.x >> 6;
    const int lane = threadIdx.x & 63;
    const int row = blockIdx.x * 4 + wave;
    float s[8] = {0.f, 0.f, 0.f, 0.f, 0.f, 0.f, 0.f, 0.f};
    #pragma unroll
    for (int t = 0; t < D / 64; ++t) {
        const int k = lane + t * 64;
        const float w0 = Wh0[(size_t)row * D + k];
        const float w1 = Wh1[(size_t)row * D + k];
        s[0] = fmaf(w0, a[k],      s[0]);  s[1] = fmaf(w1, a[D + k],  s[1]);
        s[2] = fmaf(w0, n1[k],     s[2]);  s[3] = fmaf(w1, n1[D + k], s[3]);
        s[4] = fmaf(w0, n2[k],     s[4]);  s[5] = fmaf(w1, n2[D + k], s[5]);
        s[6] = fmaf(w0, n3[k],     s[6]);  s[7] = fmaf(w1, n3[D + k], s[7]);
    }
    #pragma unroll
    for (int v = 0; v < 8; ++v) {
        float x = s[v];
        #pragma unroll
        for (int off = 32; off; off >>= 1) x += __shfl_xor(x, off);
        if (lane == 0) svec[v * BN_TOT + row] = x;
    }
}

// K3: score + per-(b,j) partial online max/sumexp
__global__ __launch_bounds__(256) void colstat_kernel(
    const int* __restrict__ e1, const int* __restrict__ e2,
    const int* __restrict__ e3, const float* __restrict__ svec,
    float* __restrict__ score, float* __restrict__ pm, float* __restrict__ pl) {
    const int b = blockIdx.z;
    const int i0 = blockIdx.y * ISPAN;
    const int j = blockIdx.x * 256 + threadIdx.x;
    const int bn = b * N;
    const float va = svec[1 * BN_TOT + bn + j];
    const float v1 = svec[3 * BN_TOT + bn + j];
    const float v2 = svec[5 * BN_TOT + bn + j];
    const float v3 = svec[7 * BN_TOT + bn + j];
    float m = -1e30f, l = 0.f;
    #pragma unroll 4
    for (int i = i0; i < i0 + ISPAN; ++i) {
        const float ua = svec[0 * BN_TOT + bn + i];
        const float u1 = svec[2 * BN_TOT + bn + i];
        const float u2 = svec[4 * BN_TOT + bn + i];
        const float u3 = svec[6 * BN_TOT + bn + i];
        const size_t eoff = (size_t)(bn + i) * N + j;
        float s = leaky(ua + va);
        float acc = 0.f;
        acc += (e1[eoff] > 0) ? leaky(u1 + v1) : 0.f;
        acc += (e2[eoff] > 0) ? leaky(u2 + v2) : 0.f;
        acc += (e3[eoff] > 0) ? leaky(u3 + v3) : 0.f;
        s = fmaf(SCALE, acc, s);
        score[eoff] = s;
        const float mn = fmaxf(m, s);
        l = l * __expf(m - mn) + __expf(s - mn);
        m = mn;
    }
    const size_t po = (size_t)(b * NSPLIT + blockIdx.y) * N + j;
    pm[po] = m;
    pl[po] = l;
}

// K4: combine partials -> cst = m* + log(l*)
__global__ __launch_bounds__(256) void combine_kernel(
    const float* __restrict__ pm, const float* __restrict__ pl,
    float* __restrict__ cst) {
    const int idx = blockIdx.x * 256 + threadIdx.x;
    const int b = idx / N, j = idx % N;
    float m = -1e30f;
    #pragma unroll
    for (int s = 0; s < NSPLIT; ++s)
        m = fmaxf(m, pm[(size_t)(b * NSPLIT + s) * N + j]);
    float l = 0.f;
    #pragma unroll
    for (int s = 0; s < NSPLIT; ++s) {
        const size_t o = (size_t)(b * NSPLIT + s) * N + j;
        l += pl[o] * __expf(pm[o] - m);
    }
    cst[idx] = m + logf(l);
}

// K4b: score fp32 -> attention split32, IN PLACE (per-thread exact 32B alias).
// grid 8192 x 256
__global__ __launch_bounds__(256) void abuild_kernel(
    char* __restrict__ scoreA, const float* __restrict__ cst) {
    const size_t cidx = (size_t)blockIdx.x * 256 + threadIdx.x;   // 2,097,152 chunks
    const int b = (int)(cidx >> 19);            // 2^19 chunks per batch
    const int j0 = ((int)cidx & 255) * 8;       // 256 chunks per row
    float v[8], c[8];
    *(float4*)&v[0] = *(const float4*)(scoreA + cidx * 32);
    *(float4*)&v[4] = *(const float4*)(scoreA + cidx * 32 + 16);
    *(float4*)&c[0] = *(const float4*)&cst[b * N + j0];
    *(float4*)&c[4] = *(const float4*)&cst[b * N + j0 + 4];
    short h[8], l[8];
    #pragma unroll
    for (int e = 0; e < 8; ++e) split2(__expf(v[e] - c[e]), h[e], l[e]);
    *(bf16x8*)(scoreA + cidx * 32) = bf16x8{h[0],h[1],h[2],h[3],h[4],h[5],h[6],h[7]};
    *(bf16x8*)(scoreA + cidx * 32 + 16) = bf16x8{l[0],l[1],l[2],l[3],l[4],l[5],l[6],l[7]};
}

// K5: out = elu(attention @ Wh1). grid (6, 16, 4) x 256, K = 2048.
__global__ __launch_bounds__(256, 2) void av_mfma(
    const char* __restrict__ scoreA, const char* __restrict__ Vts,
    float* __restrict__ out) {
    __shared__ short lds[4 * 8192];
    const int tid = threadIdx.x, wid = tid >> 6, lane = tid & 63;
    const int b = blockIdx.z;
    const int i0 = blockIdx.y * 128, d0 = blockIdx.x * 128;
    const char* Asrc = scoreA + ((size_t)(b * N + i0)) * 8192;   // A[i][j] split32
    const char* Bsrc = Vts + ((size_t)(b * D + d0)) * 8192;      // Vt[d][j] split32
    f32x4 acc[4][4] = {};
    mfma_core(Asrc, 8192, Bsrc, 8192, N / 64, lds, acc, wid, lane);

    const int wr = wid >> 1, wc = wid & 1;
    const int lrow = lane & 15, kg = lane >> 4;
    #pragma unroll
    for (int m = 0; m < 4; ++m)
        #pragma unroll
        for (int n = 0; n < 4; ++n) {
            const int rowb = i0 + wr * 64 + m * 16 + kg * 4;
            const int col = d0 + wc * 64 + n * 16 + lrow;
            #pragma unroll
            for (int r = 0; r < 4; ++r) {
                const float x = acc[m][n][r];
                out[((size_t)(b * N + rowb + r)) * D + col] = x > 0.f ? x : expm1f(x);
            }
        }
}

// ---------------------------------------------------------------------------
extern "C" void kernel_launch(void* const* d_in, const int* in_sizes, int n_in,
                              void* d_out, int out_size, void* d_ws, size_t ws_size,
                              hipStream_t stream) {
    const float* h0  = (const float*)d_in[0];
    const float* h1  = (const float*)d_in[1];
    const float* nl1 = (const float*)d_in[2];
    const int*   e1  = (const int*)d_in[3];
    const float* nl2 = (const float*)d_in[4];
    const int*   e2  = (const int*)d_in[5];
    const float* nl3 = (const float*)d_in[6];
    const int*   e3  = (const int*)d_in[7];
    const float* W   = (const float*)d_in[8];
    const float* a   = (const float*)d_in[9];
    float* out = (float*)d_out;

    // workspace (139.5 MB). Region 0 (67.1 MB) is time-shared:
    //   phase A: Wh0 fp32 (25.2) + Wh1 fp32 (25.2)   [gemm -> svec]
    //   phase B: score fp32 -> attention split32      [colstat -> av]
    char* ws = (char*)d_ws;
    char*  scoreA = ws;
    float* Wh0 = (float*)ws;
    float* Wh1 = (float*)(ws + 25165824);
    char*  hs0 = ws + 67108864;
    char*  hs1 = ws + 92274688;
    char*  Wts = ws + 117440512;
    char*  Vts = ws + 119799808;
    float* svec = (float*)(ws + 144965632);
    float* pm   = (float*)(ws + 145227776);
    float* pl   = (float*)(ws + 145752064);
    float* cst  = (float*)(ws + 146276352);

    split_h_kernel<<<dim3(3072, 2), 256, 0, stream>>>(h0, h1, hs0, hs1);
    split_wt_kernel<<<288, 256, 0, stream>>>(W, Wts);
    gemm_wh_mfma<<<dim3(6, 64, 2), 256, 0, stream>>>(hs0, hs1, Wts, Wh0, Wh1, Vts);
    svec_kernel<<<2048, 256, 0, stream>>>(Wh0, Wh1, a, nl1, nl2, nl3, svec);
    colstat_kernel<<<dim3(8, 16, 4), 256, 0, stream>>>(e1, e2, e3, svec,
                                                       (float*)scoreA, pm, pl);
    combine_kernel<<<32, 256, 0, stream>>>(pm, pl, cst);
    abuild_kernel<<<8192, 256, 0, stream>>>(scoreA, cst);
    av_mfma<<<dim3(6, 16, 4), 256, 0, stream>>>(scoreA, Vts, out);
}

// Round 7
// 402.181 us; speedup vs baseline: 2.2286x; 1.1544x over previous
//
#include <hip/hip_runtime.h>
#include <math.h>

// GATLayer fused, round 7 (= round-5 kernel, resubmitted after 2x broker timeout):
// projection associativity (h·(Wv)) removes Wh0/Wh1; colstat writes P=exp(s)
// bf16 directly (max-free softmax, abuild eliminated); 1/colsum folded into V.
// Pipeline: wvec -> svec -> colstat(P,pl) -> combine(t) -> split_h1 -> split_wtb
//           -> gemm_v (h1@W -> V*t, split-bf16) -> av (P @ V, +elu)

#define B 4
#define N 2048
#define D 768
#define BN_TOT (B * N)          // 8192
#define NSPLIT 64
#define ISPAN (N / NSPLIT)      // 32

constexpr float ALPHA = 0.2f;
constexpr float SCALE = 0.01f;

typedef __attribute__((ext_vector_type(8))) short bf16x8;   // 8 bf16 = 4 VGPR
typedef __attribute__((ext_vector_type(4))) short short4v;
typedef __attribute__((ext_vector_type(4))) float f32x4;

__device__ __forceinline__ float leaky(float x) { return x > 0.f ? x : ALPHA * x; }

// fp32 -> bf16 hi + bf16 lo (truncated hi; residual exact -> ~16-bit mantissa)
__device__ __forceinline__ void split2(float x, short& h, short& l) {
    unsigned bx = __float_as_uint(x);
    h = (short)(bx >> 16);
    float r = x - __uint_as_float(bx & 0xffff0000u);
    l = (short)(__float_as_uint(r) >> 16);
}

__device__ __forceinline__ unsigned short rne_bf16(float x) {
    unsigned bx = __float_as_uint(x);
    bx += 0x7fffu + ((bx >> 16) & 1u);
    return (unsigned short)(bx >> 16);
}
__device__ __forceinline__ float bf16f(unsigned short h) {
    return __uint_as_float(((unsigned)h) << 16);
}

__device__ __forceinline__ void gload16(const void* g, void* l) {
    __builtin_amdgcn_global_load_lds(
        (const __attribute__((address_space(1))) void*)g,
        (__attribute__((address_space(3))) void*)l, 16, 0, 0);
}

// ---------------------------------------------------------------------------
// K0: wv[v][k] = sum_d W[k,d]*vec_v[d];  v = (a,n1,n2,n3) x (lo-half, hi-half).
// grid 192 x 256 (wave per k)
// ---------------------------------------------------------------------------
__global__ __launch_bounds__(256) void wvec_kernel(
    const float* __restrict__ W, const float* __restrict__ a,
    const float* __restrict__ n1, const float* __restrict__ n2,
    const float* __restrict__ n3, float* __restrict__ wv) {
    const int wave = threadIdx.x >> 6, lane = threadIdx.x & 63;
    const int k = blockIdx.x * 4 + wave;
    const float* wr = W + (size_t)k * D;
    float s[8] = {0.f, 0.f, 0.f, 0.f, 0.f, 0.f, 0.f, 0.f};
    #pragma unroll
    for (int t = 0; t < D / 64; ++t) {
        const int d = lane + t * 64;
        const float w = wr[d];
        s[0] = fmaf(w, a[d],      s[0]);  s[1] = fmaf(w, a[D + d],  s[1]);
        s[2] = fmaf(w, n1[d],     s[2]);  s[3] = fmaf(w, n1[D + d], s[3]);
        s[4] = fmaf(w, n2[d],     s[4]);  s[5] = fmaf(w, n2[D + d], s[5]);
        s[6] = fmaf(w, n3[d],     s[6]);  s[7] = fmaf(w, n3[D + d], s[7]);
    }
    #pragma unroll
    for (int v = 0; v < 8; ++v) {
        float x = s[v];
        #pragma unroll
        for (int off = 32; off; off >>= 1) x += __shfl_xor(x, off);
        if (lane == 0) wv[v * D + k] = x;
    }
}

// ---------------------------------------------------------------------------
// K1: svec[v][b*N+row] = h{0|1}[row,:] . wv[v]   (fp32 exact path, no GEMM)
// grid 2048 x 256 (wave per row)
// ---------------------------------------------------------------------------
__global__ __launch_bounds__(256) void svec_kernel(
    const float* __restrict__ h0, const float* __restrict__ h1,
    const float* __restrict__ wv, float* __restrict__ svec) {
    __shared__ float wvs[8 * D];   // 24 KB
    for (int x = threadIdx.x; x < 8 * D; x += 256) wvs[x] = wv[x];
    __syncthreads();
    const int wave = threadIdx.x >> 6, lane = threadIdx.x & 63;
    const int row = blockIdx.x * 4 + wave;
    float s[8] = {0.f, 0.f, 0.f, 0.f, 0.f, 0.f, 0.f, 0.f};
    #pragma unroll
    for (int t = 0; t < D / 64; ++t) {
        const int k = lane + t * 64;
        const float w0 = h0[(size_t)row * D + k];
        const float w1 = h1[(size_t)row * D + k];
        s[0] = fmaf(w0, wvs[0 * D + k], s[0]);  s[1] = fmaf(w1, wvs[1 * D + k], s[1]);
        s[2] = fmaf(w0, wvs[2 * D + k], s[2]);  s[3] = fmaf(w1, wvs[3 * D + k], s[3]);
        s[4] = fmaf(w0, wvs[4 * D + k], s[4]);  s[5] = fmaf(w1, wvs[5 * D + k], s[5]);
        s[6] = fmaf(w0, wvs[6 * D + k], s[6]);  s[7] = fmaf(w1, wvs[7 * D + k], s[7]);
    }
    #pragma unroll
    for (int v = 0; v < 8; ++v) {
        float x = s[v];
        #pragma unroll
        for (int off = 32; off; off >>= 1) x += __shfl_xor(x, off);
        if (lane == 0) svec[v * BN_TOT + row] = x;
    }
}

// ---------------------------------------------------------------------------
// K2: P[b,i,j] = bf16(exp(s_ij)); pl partial column sums of the ROUNDED P.
// 4 j per thread (int4 edge loads, 8B P stores). grid (2, 64, 4) x 256
// ---------------------------------------------------------------------------
__global__ __launch_bounds__(256) void colstat_kernel(
    const int* __restrict__ e1, const int* __restrict__ e2,
    const int* __restrict__ e3, const float* __restrict__ svec,
    char* __restrict__ P, float* __restrict__ pl) {
    const int b = blockIdx.z;
    const int i0 = blockIdx.y * ISPAN;
    const int j0 = blockIdx.x * 1024 + threadIdx.x * 4;
    const int bn = b * N;
    const float4 va = *(const float4*)&svec[1 * BN_TOT + bn + j0];
    const float4 v1 = *(const float4*)&svec[3 * BN_TOT + bn + j0];
    const float4 v2 = *(const float4*)&svec[5 * BN_TOT + bn + j0];
    const float4 v3 = *(const float4*)&svec[7 * BN_TOT + bn + j0];
    const float vaa[4] = {va.x, va.y, va.z, va.w};
    const float v1a[4] = {v1.x, v1.y, v1.z, v1.w};
    const float v2a[4] = {v2.x, v2.y, v2.z, v2.w};
    const float v3a[4] = {v3.x, v3.y, v3.z, v3.w};
    float l[4] = {0.f, 0.f, 0.f, 0.f};
    for (int i = i0; i < i0 + ISPAN; ++i) {
        const float ua = svec[0 * BN_TOT + bn + i];
        const float u1 = svec[2 * BN_TOT + bn + i];
        const float u2 = svec[4 * BN_TOT + bn + i];
        const float u3 = svec[6 * BN_TOT + bn + i];
        const size_t eoff = (size_t)(bn + i) * N + j0;
        const int4 m1 = *(const int4*)&e1[eoff];
        const int4 m2 = *(const int4*)&e2[eoff];
        const int4 m3 = *(const int4*)&e3[eoff];
        const int m1a[4] = {m1.x, m1.y, m1.z, m1.w};
        const int m2a[4] = {m2.x, m2.y, m2.z, m2.w};
        const int m3a[4] = {m3.x, m3.y, m3.z, m3.w};
        unsigned short pb[4];
        #pragma unroll
        for (int c = 0; c < 4; ++c) {
            float s = leaky(ua + vaa[c]);
            float at = 0.f;
            at += (m1a[c] > 0) ? leaky(u1 + v1a[c]) : 0.f;
            at += (m2a[c] > 0) ? leaky(u2 + v2a[c]) : 0.f;
            at += (m3a[c] > 0) ? leaky(u3 + v3a[c]) : 0.f;
            s = fmaf(SCALE, at, s);
            pb[c] = rne_bf16(__expf(s));
            l[c] += bf16f(pb[c]);    // normalize over exactly what av consumes
        }
        *(short4v*)(P + ((size_t)(bn + i) * N + j0) * 2) =
            short4v{(short)pb[0], (short)pb[1], (short)pb[2], (short)pb[3]};
    }
    *(float4*)&pl[(size_t)(b * NSPLIT + blockIdx.y) * N + j0] =
        make_float4(l[0], l[1], l[2], l[3]);
}

// ---------------------------------------------------------------------------
// K3: t[b*N+j] = 1 / sum_s pl  (attention = P * t, folded into V)
// ---------------------------------------------------------------------------
__global__ __launch_bounds__(256) void combine_kernel(
    const float* __restrict__ pl, float* __restrict__ tsc) {
    const int idx = blockIdx.x * 256 + threadIdx.x;   // b*N + j
    const int b = idx >> 11, j = idx & (N - 1);
    float sum = 0.f;
    #pragma unroll
    for (int s = 0; s < NSPLIT; ++s)
        sum += pl[(size_t)(b * NSPLIT + s) * N + j];
    tsc[idx] = 1.0f / sum;
}

// ---------------------------------------------------------------------------
// K4: h1 -> split32 (hi/lo bf16 pairs per 8 elems). grid 3072 x 256
// ---------------------------------------------------------------------------
__global__ __launch_bounds__(256) void split_h1_kernel(
    const float* __restrict__ h1, char* __restrict__ hs1) {
    const size_t cidx = (size_t)blockIdx.x * 256 + threadIdx.x;   // 786432
    float v[8];
    *(float4*)&v[0] = *(const float4*)&h1[cidx * 8];
    *(float4*)&v[4] = *(const float4*)&h1[cidx * 8 + 4];
    short h[8], l[8];
    #pragma unroll
    for (int e = 0; e < 8; ++e) split2(v[e], h[e], l[e]);
    *(bf16x8*)(hs1 + cidx * 32) = bf16x8{h[0],h[1],h[2],h[3],h[4],h[5],h[6],h[7]};
    *(bf16x8*)(hs1 + cidx * 32 + 16) = bf16x8{l[0],l[1],l[2],l[3],l[4],l[5],l[6],l[7]};
}

// ---------------------------------------------------------------------------
// K5: W[k][n] -> Wtb[n][k] plain bf16 (RNE). grid 288 x 256
// ---------------------------------------------------------------------------
__global__ __launch_bounds__(256) void split_wtb_kernel(
    const float* __restrict__ W, char* __restrict__ Wtb) {
    const int cidx = blockIdx.x * 256 + threadIdx.x;   // 768*96 = 73728
    const int n = cidx / (D / 8);
    const int k0 = (cidx % (D / 8)) * 8;
    short h[8];
    #pragma unroll
    for (int e = 0; e < 8; ++e) h[e] = (short)rne_bf16(W[(size_t)(k0 + e) * D + n]);
    *(bf16x8*)(Wtb + (size_t)cidx * 16) = bf16x8{h[0],h[1],h[2],h[3],h[4],h[5],h[6],h[7]};
}

// ---------------------------------------------------------------------------
// K6: V = (h1 @ W) * t, written as Vt[b][d][j] split32.
// 64x128 tile (rows x d), BK=64, 4 waves 2x2 (32x64/wave), 2-term MFMA
// (Ah*W + Al*W). LDS 32 KB: Ah 8K | Al 8K | Bw 16K. grid (6, 128) x 256
// ---------------------------------------------------------------------------
__global__ __launch_bounds__(256, 2) void gemm_v(
    const char* __restrict__ hs1, const char* __restrict__ Wtb,
    const float* __restrict__ tsc, char* __restrict__ Vts) {
    __shared__ char lds[32768];
    const int tid = threadIdx.x, wid = tid >> 6, lane = tid & 63;
    const int row0 = blockIdx.y * 64;     // global h1-row (b*N+j)
    const int col0 = blockIdx.x * 128;    // d
    const char* Asrc = hs1 + (size_t)row0 * 3072;
    const char* Bsrc = Wtb + (size_t)col0 * 1536;
    const int wr = wid >> 1, wc = wid & 1;
    const int lrow = lane & 15, kg = lane >> 4;
    f32x4 acc[2][4] = {};

    for (int kt = 0; kt < D / 64; ++kt) {
        __syncthreads();
        #pragma unroll
        for (int s = 0; s < 2; ++s) {      // A: 8 segs x 1KB (hi+lo)
            const int seg = s * 4 + wid;
            const int row = seg * 8 + (lane >> 3);          // 0..63
            const int c = (lane & 7) ^ (row & 7);
            const char* ga = Asrc + (size_t)kt * 256 + (size_t)row * 3072 + c * 32;
            gload16(ga,      lds + seg * 1024);
            gload16(ga + 16, lds + 8192 + seg * 1024);
        }
        #pragma unroll
        for (int s = 0; s < 4; ++s) {      // B: 16 segs x 1KB
            const int seg = s * 4 + wid;
            const int row = seg * 8 + (lane >> 3);          // 0..127
            const int c = (lane & 7) ^ (row & 7);
            gload16(Bsrc + (size_t)kt * 128 + (size_t)row * 1536 + c * 16,
                    lds + 16384 + seg * 1024);
        }
        __syncthreads();
        #pragma unroll
        for (int ks = 0; ks < 2; ++ks) {
            bf16x8 ah[2], al[2], bw[4];
            #pragma unroll
            for (int m = 0; m < 2; ++m) {
                const int r = wr * 32 + m * 16 + lrow;
                const int c = (ks * 4 + kg) ^ (r & 7);
                ah[m] = *(const bf16x8*)(lds + r * 128 + c * 16);
                al[m] = *(const bf16x8*)(lds + 8192 + r * 128 + c * 16);
            }
            #pragma unroll
            for (int n = 0; n < 4; ++n) {
                const int r = wc * 64 + n * 16 + lrow;
                const int c = (ks * 4 + kg) ^ (r & 7);
                bw[n] = *(const bf16x8*)(lds + 16384 + r * 128 + c * 16);
            }
            #pragma unroll
            for (int m = 0; m < 2; ++m)
                #pragma unroll
                for (int n = 0; n < 4; ++n) {
                    acc[m][n] = __builtin_amdgcn_mfma_f32_16x16x32_bf16(ah[m], bw[n], acc[m][n], 0, 0, 0);
                    acc[m][n] = __builtin_amdgcn_mfma_f32_16x16x32_bf16(al[m], bw[n], acc[m][n], 0, 0, 0);
                }
        }
    }
    #pragma unroll
    for (int m = 0; m < 2; ++m)
        #pragma unroll
        for (int n = 0; n < 4; ++n) {
            const int rowb = row0 + wr * 32 + m * 16 + kg * 4;   // b*N + j
            const int col = col0 + wc * 64 + n * 16 + lrow;      // d
            const int bq = rowb >> 11, j = rowb & (N - 1);
            short h4[4], l4[4];
            #pragma unroll
            for (int r = 0; r < 4; ++r) {
                const float x = acc[m][n][r] * tsc[bq * N + j + r];
                split2(x, h4[r], l4[r]);
            }
            char* base = Vts + ((size_t)(bq * D + col)) * 8192 + (j >> 3) * 32 + (j & 7) * 2;
            *(short4v*)base        = short4v{h4[0], h4[1], h4[2], h4[3]};
            *(short4v*)(base + 16) = short4v{l4[0], l4[1], l4[2], l4[3]};
        }
}

// ---------------------------------------------------------------------------
// K7: out = elu(P @ V).  A = P plain bf16, B = V split (2 MFMA: P*Vh + P*Vl).
// 64x128 tile (i x d), BK=64, LDS 40 KB: Ap 8K | Bh 16K | Bl 16K.
// grid (6, 32, 4) x 256
// ---------------------------------------------------------------------------
__global__ __launch_bounds__(256, 2) void av_kernel(
    const char* __restrict__ P, const char* __restrict__ Vts,
    float* __restrict__ out) {
    __shared__ char lds[40960];
    const int tid = threadIdx.x, wid = tid >> 6, lane = tid & 63;
    const int b = blockIdx.z;
    const int i0 = blockIdx.y * 64, d0 = blockIdx.x * 128;
    const char* Asrc = P + ((size_t)(b * N + i0)) * 4096;     // P row = 4 KB
    const char* Bsrc = Vts + ((size_t)(b * D + d0)) * 8192;   // Vt row = 8 KB
    const int wr = wid >> 1, wc = wid & 1;
    const int lrow = lane & 15, kg = lane >> 4;
    f32x4 acc[2][4] = {};

    for (int kt = 0; kt < N / 64; ++kt) {
        __syncthreads();
        #pragma unroll
        for (int s = 0; s < 2; ++s) {      // A: 8 segs
            const int seg = s * 4 + wid;
            const int row = seg * 8 + (lane >> 3);          // 0..63 (i-local)
            const int c = (lane & 7) ^ (row & 7);
            gload16(Asrc + (size_t)kt * 128 + (size_t)row * 4096 + c * 16,
                    lds + seg * 1024);
        }
        #pragma unroll
        for (int s = 0; s < 4; ++s) {      // B: 16 segs (hi+lo)
            const int seg = s * 4 + wid;
            const int row = seg * 8 + (lane >> 3);          // 0..127 (d-local)
            const int c = (lane & 7) ^ (row & 7);
            const char* gb = Bsrc + (size_t)kt * 256 + (size_t)row * 8192 + c * 32;
            gload16(gb,      lds + 8192 + seg * 1024);
            gload16(gb + 16, lds + 24576 + seg * 1024);
        }
        __syncthreads();
        #pragma unroll
        for (int ks = 0; ks < 2; ++ks) {
            bf16x8 ap[2], bh[4], bl[4];
            #pragma unroll
            for (int m = 0; m < 2; ++m) {
                const int r = wr * 32 + m * 16 + lrow;
                const int c = (ks * 4 + kg) ^ (r & 7);
                ap[m] = *(const bf16x8*)(lds + r * 128 + c * 16);
            }
            #pragma unroll
            for (int n = 0; n < 4; ++n) {
                const int r = wc * 64 + n * 16 + lrow;
                const int c = (ks * 4 + kg) ^ (r & 7);
                bh[n] = *(const bf16x8*)(lds + 8192 + r * 128 + c * 16);
                bl[n] = *(const bf16x8*)(lds + 24576 + r * 128 + c * 16);
            }
            #pragma unroll
            for (int m = 0; m < 2; ++m)
                #pragma unroll
                for (int n = 0; n < 4; ++n) {
                    acc[m][n] = __builtin_amdgcn_mfma_f32_16x16x32_bf16(ap[m], bh[n], acc[m][n], 0, 0, 0);
                    acc[m][n] = __builtin_amdgcn_mfma_f32_16x16x32_bf16(ap[m], bl[n], acc[m][n], 0, 0, 0);
                }
        }
    }
    #pragma unroll
    for (int m = 0; m < 2; ++m)
        #pragma unroll
        for (int n = 0; n < 4; ++n) {
            const int rowi = i0 + wr * 32 + m * 16 + kg * 4;
            const int col = d0 + wc * 64 + n * 16 + lrow;
            #pragma unroll
            for (int r = 0; r < 4; ++r) {
                const float x = acc[m][n][r];
                out[((size_t)(b * N + rowi + r)) * D + col] = x > 0.f ? x : expm1f(x);
            }
        }
}

// ---------------------------------------------------------------------------
extern "C" void kernel_launch(void* const* d_in, const int* in_sizes, int n_in,
                              void* d_out, int out_size, void* d_ws, size_t ws_size,
                              hipStream_t stream) {
    const float* h0  = (const float*)d_in[0];
    const float* h1  = (const float*)d_in[1];
    const float* nl1 = (const float*)d_in[2];
    const int*   e1  = (const int*)d_in[3];
    const float* nl2 = (const float*)d_in[4];
    const int*   e2  = (const int*)d_in[5];
    const float* nl3 = (const float*)d_in[6];
    const int*   e3  = (const int*)d_in[7];
    const float* W   = (const float*)d_in[8];
    const float* a   = (const float*)d_in[9];
    float* out = (float*)d_out;

    // workspace layout (87.5 MB)
    char* ws = (char*)d_ws;
    char*  P    = ws;                          // 33,554,432  B*N*N bf16
    char*  hs1  = ws + 33554432;               // 25,165,824  split32
    char*  Wtb  = ws + 58720256;               //  1,179,648  bf16 [n][k]
    char*  Vts  = ws + 59899904;               // 25,165,824  split32 [b][d][j]
    float* wv   = (float*)(ws + 85065728);     //     24,576  8 x 768
    float* svec = (float*)(ws + 85090304);     //    262,144  8 x 8192
    float* pl   = (float*)(ws + 85352448);     //  2,097,152  64 x 8192
    float* tsc  = (float*)(ws + 87449600);     //     32,768  8192

    wvec_kernel<<<192, 256, 0, stream>>>(W, a, nl1, nl2, nl3, wv);
    svec_kernel<<<2048, 256, 0, stream>>>(h0, h1, wv, svec);
    colstat_kernel<<<dim3(2, NSPLIT, B), 256, 0, stream>>>(e1, e2, e3, svec, P, pl);
    combine_kernel<<<BN_TOT / 256, 256, 0, stream>>>(pl, tsc);
    split_h1_kernel<<<3072, 256, 0, stream>>>(h1, hs1);
    split_wtb_kernel<<<288, 256, 0, stream>>>(W, Wtb);
    gemm_v<<<dim3(6, 128), 256, 0, stream>>>(hs1, Wtb, tsc, Vts);
    av_kernel<<<dim3(6, 32, 4), 256, 0, stream>>>(P, Vts, out);
}

// Round 8
// 383.242 us; speedup vs baseline: 2.3388x; 1.0494x over previous
//
#include <hip/hip_runtime.h>
#include <math.h>

// GATLayer fused, round 8: colstat occupancy x4 (NSPLIT 64->256, 2048 blocks);
// svec vectorized (float4) and fused with split_h1 (h1 read once).
// Pipeline: wvec -> svec_split (svec + hs1) -> colstat(P,pl) -> combine(t)
//           -> split_wtb -> gemm_v (h1@W -> V*t, split-bf16) -> av (P@V, +elu)

#define B 4
#define N 2048
#define D 768
#define BN_TOT (B * N)          // 8192
#define NSPLIT 256
#define ISPAN (N / NSPLIT)      // 8

constexpr float ALPHA = 0.2f;
constexpr float SCALE = 0.01f;

typedef __attribute__((ext_vector_type(8))) short bf16x8;   // 8 bf16 = 4 VGPR
typedef __attribute__((ext_vector_type(4))) short short4v;
typedef __attribute__((ext_vector_type(4))) float f32x4;

__device__ __forceinline__ float leaky(float x) { return x > 0.f ? x : ALPHA * x; }

// fp32 -> bf16 hi + bf16 lo (truncated hi; residual exact -> ~16-bit mantissa)
__device__ __forceinline__ void split2(float x, short& h, short& l) {
    unsigned bx = __float_as_uint(x);
    h = (short)(bx >> 16);
    float r = x - __uint_as_float(bx & 0xffff0000u);
    l = (short)(__float_as_uint(r) >> 16);
}

__device__ __forceinline__ unsigned short rne_bf16(float x) {
    unsigned bx = __float_as_uint(x);
    bx += 0x7fffu + ((bx >> 16) & 1u);
    return (unsigned short)(bx >> 16);
}
__device__ __forceinline__ float bf16f(unsigned short h) {
    return __uint_as_float(((unsigned)h) << 16);
}

__device__ __forceinline__ void gload16(const void* g, void* l) {
    __builtin_amdgcn_global_load_lds(
        (const __attribute__((address_space(1))) void*)g,
        (__attribute__((address_space(3))) void*)l, 16, 0, 0);
}

// ---------------------------------------------------------------------------
// K0: wv[v][k] = sum_d W[k,d]*vec_v[d];  v = (a,n1,n2,n3) x (lo, hi halves).
// grid 192 x 256 (wave per k)
// ---------------------------------------------------------------------------
__global__ __launch_bounds__(256) void wvec_kernel(
    const float* __restrict__ W, const float* __restrict__ a,
    const float* __restrict__ n1, const float* __restrict__ n2,
    const float* __restrict__ n3, float* __restrict__ wv) {
    const int wave = threadIdx.x >> 6, lane = threadIdx.x & 63;
    const int k = blockIdx.x * 4 + wave;
    const float* wr = W + (size_t)k * D;
    float s[8] = {0.f, 0.f, 0.f, 0.f, 0.f, 0.f, 0.f, 0.f};
    #pragma unroll
    for (int t = 0; t < D / 64; ++t) {
        const int d = lane + t * 64;
        const float w = wr[d];
        s[0] = fmaf(w, a[d],      s[0]);  s[1] = fmaf(w, a[D + d],  s[1]);
        s[2] = fmaf(w, n1[d],     s[2]);  s[3] = fmaf(w, n1[D + d], s[3]);
        s[4] = fmaf(w, n2[d],     s[4]);  s[5] = fmaf(w, n2[D + d], s[5]);
        s[6] = fmaf(w, n3[d],     s[6]);  s[7] = fmaf(w, n3[D + d], s[7]);
    }
    #pragma unroll
    for (int v = 0; v < 8; ++v) {
        float x = s[v];
        #pragma unroll
        for (int off = 32; off; off >>= 1) x += __shfl_xor(x, off);
        if (lane == 0) wv[v * D + k] = x;
    }
}

// ---------------------------------------------------------------------------
// K1: svec[v][row] = h{0|1}[row,:].wv[v]  (float4 loads)  +  h1 -> hs1 split32.
// grid 2048 x 256 (wave per row, 4 rows/block)
// ---------------------------------------------------------------------------
__global__ __launch_bounds__(256) void svec_split_kernel(
    const float* __restrict__ h0, const float* __restrict__ h1,
    const float* __restrict__ wv, float* __restrict__ svec,
    char* __restrict__ hs1) {
    __shared__ float wvs[8 * D];   // 24 KB
    for (int x = threadIdx.x; x < 8 * D; x += 256) wvs[x] = wv[x];
    __syncthreads();
    const int wave = threadIdx.x >> 6, lane = threadIdx.x & 63;
    const int row = blockIdx.x * 4 + wave;
    float s[8] = {0.f, 0.f, 0.f, 0.f, 0.f, 0.f, 0.f, 0.f};
    #pragma unroll
    for (int t = 0; t < 3; ++t) {
        const int k0 = t * 256 + lane * 4;
        const float4 a0 = *(const float4*)&h0[(size_t)row * D + k0];
        const float4 a1 = *(const float4*)&h1[(size_t)row * D + k0];
        #pragma unroll
        for (int v = 0; v < 8; v += 2) {
            const float4 w0 = *(const float4*)&wvs[v * D + k0];
            const float4 w1 = *(const float4*)&wvs[(v + 1) * D + k0];
            s[v]     = fmaf(a0.x, w0.x, fmaf(a0.y, w0.y,
                       fmaf(a0.z, w0.z, fmaf(a0.w, w0.w, s[v]))));
            s[v + 1] = fmaf(a1.x, w1.x, fmaf(a1.y, w1.y,
                       fmaf(a1.z, w1.z, fmaf(a1.w, w1.w, s[v + 1]))));
        }
        // fused split_h1: write this float4 of h1 as split32 hi/lo (8B each)
        short hh[4], ll[4];
        split2(a1.x, hh[0], ll[0]); split2(a1.y, hh[1], ll[1]);
        split2(a1.z, hh[2], ll[2]); split2(a1.w, hh[3], ll[3]);
        char* base = hs1 + (size_t)row * 3072 + (k0 >> 3) * 32 + (k0 & 7) * 2;
        *(short4v*)base        = short4v{hh[0], hh[1], hh[2], hh[3]};
        *(short4v*)(base + 16) = short4v{ll[0], ll[1], ll[2], ll[3]};
    }
    #pragma unroll
    for (int v = 0; v < 8; ++v) {
        float x = s[v];
        #pragma unroll
        for (int off = 32; off; off >>= 1) x += __shfl_xor(x, off);
        if (lane == 0) svec[v * BN_TOT + row] = x;
    }
}

// ---------------------------------------------------------------------------
// K2: P[b,i,j] = bf16(exp(s_ij)); pl partial column sums of the ROUNDED P.
// 4 j per thread (int4 edge loads, 8B P stores). grid (2, 256, 4) x 256
// ---------------------------------------------------------------------------
__global__ __launch_bounds__(256) void colstat_kernel(
    const int* __restrict__ e1, const int* __restrict__ e2,
    const int* __restrict__ e3, const float* __restrict__ svec,
    char* __restrict__ P, float* __restrict__ pl) {
    const int b = blockIdx.z;
    const int i0 = blockIdx.y * ISPAN;
    const int j0 = blockIdx.x * 1024 + threadIdx.x * 4;
    const int bn = b * N;
    const float4 va = *(const float4*)&svec[1 * BN_TOT + bn + j0];
    const float4 v1 = *(const float4*)&svec[3 * BN_TOT + bn + j0];
    const float4 v2 = *(const float4*)&svec[5 * BN_TOT + bn + j0];
    const float4 v3 = *(const float4*)&svec[7 * BN_TOT + bn + j0];
    const float vaa[4] = {va.x, va.y, va.z, va.w};
    const float v1a[4] = {v1.x, v1.y, v1.z, v1.w};
    const float v2a[4] = {v2.x, v2.y, v2.z, v2.w};
    const float v3a[4] = {v3.x, v3.y, v3.z, v3.w};
    float l[4] = {0.f, 0.f, 0.f, 0.f};
    #pragma unroll
    for (int i = i0; i < i0 + ISPAN; ++i) {
        const float ua = svec[0 * BN_TOT + bn + i];
        const float u1 = svec[2 * BN_TOT + bn + i];
        const float u2 = svec[4 * BN_TOT + bn + i];
        const float u3 = svec[6 * BN_TOT + bn + i];
        const size_t eoff = (size_t)(bn + i) * N + j0;
        const int4 m1 = *(const int4*)&e1[eoff];
        const int4 m2 = *(const int4*)&e2[eoff];
        const int4 m3 = *(const int4*)&e3[eoff];
        const int m1a[4] = {m1.x, m1.y, m1.z, m1.w};
        const int m2a[4] = {m2.x, m2.y, m2.z, m2.w};
        const int m3a[4] = {m3.x, m3.y, m3.z, m3.w};
        unsigned short pb[4];
        #pragma unroll
        for (int c = 0; c < 4; ++c) {
            float s = leaky(ua + vaa[c]);
            float at = 0.f;
            at += (m1a[c] > 0) ? leaky(u1 + v1a[c]) : 0.f;
            at += (m2a[c] > 0) ? leaky(u2 + v2a[c]) : 0.f;
            at += (m3a[c] > 0) ? leaky(u3 + v3a[c]) : 0.f;
            s = fmaf(SCALE, at, s);
            pb[c] = rne_bf16(__expf(s));
            l[c] += bf16f(pb[c]);    // normalize over exactly what av consumes
        }
        *(short4v*)(P + ((size_t)(bn + i) * N + j0) * 2) =
            short4v{(short)pb[0], (short)pb[1], (short)pb[2], (short)pb[3]};
    }
    *(float4*)&pl[(size_t)(b * NSPLIT + blockIdx.y) * N + j0] =
        make_float4(l[0], l[1], l[2], l[3]);
}

// ---------------------------------------------------------------------------
// K3: t[b*N+j] = 1 / sum_s pl  (attention = P * t, folded into V)
// ---------------------------------------------------------------------------
__global__ __launch_bounds__(256) void combine_kernel(
    const float* __restrict__ pl, float* __restrict__ tsc) {
    const int idx = blockIdx.x * 256 + threadIdx.x;   // b*N + j
    const int b = idx >> 11, j = idx & (N - 1);
    float sum = 0.f;
    #pragma unroll 8
    for (int s = 0; s < NSPLIT; ++s)
        sum += pl[(size_t)(b * NSPLIT + s) * N + j];
    tsc[idx] = 1.0f / sum;
}

// ---------------------------------------------------------------------------
// K5: W[k][n] -> Wtb[n][k] plain bf16 (RNE). grid 288 x 256
// ---------------------------------------------------------------------------
__global__ __launch_bounds__(256) void split_wtb_kernel(
    const float* __restrict__ W, char* __restrict__ Wtb) {
    const int cidx = blockIdx.x * 256 + threadIdx.x;   // 768*96 = 73728
    const int n = cidx / (D / 8);
    const int k0 = (cidx % (D / 8)) * 8;
    short h[8];
    #pragma unroll
    for (int e = 0; e < 8; ++e) h[e] = (short)rne_bf16(W[(size_t)(k0 + e) * D + n]);
    *(bf16x8*)(Wtb + (size_t)cidx * 16) = bf16x8{h[0],h[1],h[2],h[3],h[4],h[5],h[6],h[7]};
}

// ---------------------------------------------------------------------------
// K6: V = (h1 @ W) * t, written as Vt[b][d][j] split32.
// 64x128 tile (rows x d), BK=64, 4 waves 2x2 (32x64/wave), 2-term MFMA
// (Ah*W + Al*W). LDS 32 KB: Ah 8K | Al 8K | Bw 16K. grid (6, 128) x 256
// ---------------------------------------------------------------------------
__global__ __launch_bounds__(256, 2) void gemm_v(
    const char* __restrict__ hs1, const char* __restrict__ Wtb,
    const float* __restrict__ tsc, char* __restrict__ Vts) {
    __shared__ char lds[32768];
    const int tid = threadIdx.x, wid = tid >> 6, lane = tid & 63;
    const int row0 = blockIdx.y * 64;     // global h1-row (b*N+j)
    const int col0 = blockIdx.x * 128;    // d
    const char* Asrc = hs1 + (size_t)row0 * 3072;
    const char* Bsrc = Wtb + (size_t)col0 * 1536;
    const int wr = wid >> 1, wc = wid & 1;
    const int lrow = lane & 15, kg = lane >> 4;
    f32x4 acc[2][4] = {};

    for (int kt = 0; kt < D / 64; ++kt) {
        __syncthreads();
        #pragma unroll
        for (int s = 0; s < 2; ++s) {      // A: 8 segs x 1KB (hi+lo)
            const int seg = s * 4 + wid;
            const int row = seg * 8 + (lane >> 3);          // 0..63
            const int c = (lane & 7) ^ (row & 7);
            const char* ga = Asrc + (size_t)kt * 256 + (size_t)row * 3072 + c * 32;
            gload16(ga,      lds + seg * 1024);
            gload16(ga + 16, lds + 8192 + seg * 1024);
        }
        #pragma unroll
        for (int s = 0; s < 4; ++s) {      // B: 16 segs x 1KB
            const int seg = s * 4 + wid;
            const int row = seg * 8 + (lane >> 3);          // 0..127
            const int c = (lane & 7) ^ (row & 7);
            gload16(Bsrc + (size_t)kt * 128 + (size_t)row * 1536 + c * 16,
                    lds + 16384 + seg * 1024);
        }
        __syncthreads();
        #pragma unroll
        for (int ks = 0; ks < 2; ++ks) {
            bf16x8 ah[2], al[2], bw[4];
            #pragma unroll
            for (int m = 0; m < 2; ++m) {
                const int r = wr * 32 + m * 16 + lrow;
                const int c = (ks * 4 + kg) ^ (r & 7);
                ah[m] = *(const bf16x8*)(lds + r * 128 + c * 16);
                al[m] = *(const bf16x8*)(lds + 8192 + r * 128 + c * 16);
            }
            #pragma unroll
            for (int n = 0; n < 4; ++n) {
                const int r = wc * 64 + n * 16 + lrow;
                const int c = (ks * 4 + kg) ^ (r & 7);
                bw[n] = *(const bf16x8*)(lds + 16384 + r * 128 + c * 16);
            }
            #pragma unroll
            for (int m = 0; m < 2; ++m)
                #pragma unroll
                for (int n = 0; n < 4; ++n) {
                    acc[m][n] = __builtin_amdgcn_mfma_f32_16x16x32_bf16(ah[m], bw[n], acc[m][n], 0, 0, 0);
                    acc[m][n] = __builtin_amdgcn_mfma_f32_16x16x32_bf16(al[m], bw[n], acc[m][n], 0, 0, 0);
                }
        }
    }
    #pragma unroll
    for (int m = 0; m < 2; ++m)
        #pragma unroll
        for (int n = 0; n < 4; ++n) {
            const int rowb = row0 + wr * 32 + m * 16 + kg * 4;   // b*N + j
            const int col = col0 + wc * 64 + n * 16 + lrow;      // d
            const int bq = rowb >> 11, j = rowb & (N - 1);
            short h4[4], l4[4];
            #pragma unroll
            for (int r = 0; r < 4; ++r) {
                const float x = acc[m][n][r] * tsc[bq * N + j + r];
                split2(x, h4[r], l4[r]);
            }
            char* base = Vts + ((size_t)(bq * D + col)) * 8192 + (j >> 3) * 32 + (j & 7) * 2;
            *(short4v*)base        = short4v{h4[0], h4[1], h4[2], h4[3]};
            *(short4v*)(base + 16) = short4v{l4[0], l4[1], l4[2], l4[3]};
        }
}

// ---------------------------------------------------------------------------
// K7: out = elu(P @ V).  A = P plain bf16, B = V split (2 MFMA: P*Vh + P*Vl).
// 64x128 tile (i x d), BK=64, LDS 40 KB: Ap 8K | Bh 16K | Bl 16K.
// grid (6, 32, 4) x 256
// ---------------------------------------------------------------------------
__global__ __launch_bounds__(256, 2) void av_kernel(
    const char* __restrict__ P, const char* __restrict__ Vts,
    float* __restrict__ out) {
    __shared__ char lds[40960];
    const int tid = threadIdx.x, wid = tid >> 6, lane = tid & 63;
    const int b = blockIdx.z;
    const int i0 = blockIdx.y * 64, d0 = blockIdx.x * 128;
    const char* Asrc = P + ((size_t)(b * N + i0)) * 4096;     // P row = 4 KB
    const char* Bsrc = Vts + ((size_t)(b * D + d0)) * 8192;   // Vt row = 8 KB
    const int wr = wid >> 1, wc = wid & 1;
    const int lrow = lane & 15, kg = lane >> 4;
    f32x4 acc[2][4] = {};

    for (int kt = 0; kt < N / 64; ++kt) {
        __syncthreads();
        #pragma unroll
        for (int s = 0; s < 2; ++s) {      // A: 8 segs
            const int seg = s * 4 + wid;
            const int row = seg * 8 + (lane >> 3);          // 0..63 (i-local)
            const int c = (lane & 7) ^ (row & 7);
            gload16(Asrc + (size_t)kt * 128 + (size_t)row * 4096 + c * 16,
                    lds + seg * 1024);
        }
        #pragma unroll
        for (int s = 0; s < 4; ++s) {      // B: 16 segs (hi+lo)
            const int seg = s * 4 + wid;
            const int row = seg * 8 + (lane >> 3);          // 0..127 (d-local)
            const int c = (lane & 7) ^ (row & 7);
            const char* gb = Bsrc + (size_t)kt * 256 + (size_t)row * 8192 + c * 32;
            gload16(gb,      lds + 8192 + seg * 1024);
            gload16(gb + 16, lds + 24576 + seg * 1024);
        }
        __syncthreads();
        #pragma unroll
        for (int ks = 0; ks < 2; ++ks) {
            bf16x8 ap[2], bh[4], bl[4];
            #pragma unroll
            for (int m = 0; m < 2; ++m) {
                const int r = wr * 32 + m * 16 + lrow;
                const int c = (ks * 4 + kg) ^ (r & 7);
                ap[m] = *(const bf16x8*)(lds + r * 128 + c * 16);
            }
            #pragma unroll
            for (int n = 0; n < 4; ++n) {
                const int r = wc * 64 + n * 16 + lrow;
                const int c = (ks * 4 + kg) ^ (r & 7);
                bh[n] = *(const bf16x8*)(lds + 8192 + r * 128 + c * 16);
                bl[n] = *(const bf16x8*)(lds + 24576 + r * 128 + c * 16);
            }
            #pragma unroll
            for (int m = 0; m < 2; ++m)
                #pragma unroll
                for (int n = 0; n < 4; ++n) {
                    acc[m][n] = __builtin_amdgcn_mfma_f32_16x16x32_bf16(ap[m], bh[n], acc[m][n], 0, 0, 0);
                    acc[m][n] = __builtin_amdgcn_mfma_f32_16x16x32_bf16(ap[m], bl[n], acc[m][n], 0, 0, 0);
                }
        }
    }
    #pragma unroll
    for (int m = 0; m < 2; ++m)
        #pragma unroll
        for (int n = 0; n < 4; ++n) {
            const int rowi = i0 + wr * 32 + m * 16 + kg * 4;
            const int col = d0 + wc * 64 + n * 16 + lrow;
            #pragma unroll
            for (int r = 0; r < 4; ++r) {
                const float x = acc[m][n][r];
                out[((size_t)(b * N + rowi + r)) * D + col] = x > 0.f ? x : expm1f(x);
            }
        }
}

// ---------------------------------------------------------------------------
extern "C" void kernel_launch(void* const* d_in, const int* in_sizes, int n_in,
                              void* d_out, int out_size, void* d_ws, size_t ws_size,
                              hipStream_t stream) {
    const float* h0  = (const float*)d_in[0];
    const float* h1  = (const float*)d_in[1];
    const float* nl1 = (const float*)d_in[2];
    const int*   e1  = (const int*)d_in[3];
    const float* nl2 = (const float*)d_in[4];
    const int*   e2  = (const int*)d_in[5];
    const float* nl3 = (const float*)d_in[6];
    const int*   e3  = (const int*)d_in[7];
    const float* W   = (const float*)d_in[8];
    const float* a   = (const float*)d_in[9];
    float* out = (float*)d_out;

    // workspace layout (~94 MB)
    char* ws = (char*)d_ws;
    char*  P    = ws;                          // 33,554,432  B*N*N bf16
    char*  hs1  = ws + 33554432;               // 25,165,824  split32
    char*  Wtb  = ws + 58720256;               //  1,179,648  bf16 [n][k]
    char*  Vts  = ws + 59899904;               // 25,165,824  split32 [b][d][j]
    float* wv   = (float*)(ws + 85065728);     //     24,576  8 x 768
    float* svec = (float*)(ws + 85090304);     //    262,144  8 x 8192
    float* pl   = (float*)(ws + 85352448);     //  8,388,608  256 x 8192
    float* tsc  = (float*)(ws + 93741056);     //     32,768  8192

    wvec_kernel<<<192, 256, 0, stream>>>(W, a, nl1, nl2, nl3, wv);
    svec_split_kernel<<<2048, 256, 0, stream>>>(h0, h1, wv, svec, hs1);
    colstat_kernel<<<dim3(2, NSPLIT, B), 256, 0, stream>>>(e1, e2, e3, svec, P, pl);
    combine_kernel<<<BN_TOT / 256, 256, 0, stream>>>(pl, tsc);
    split_wtb_kernel<<<288, 256, 0, stream>>>(W, Wtb);
    gemm_v<<<dim3(6, 128), 256, 0, stream>>>(hs1, Wtb, tsc, Vts);
    av_kernel<<<dim3(6, 32, 4), 256, 0, stream>>>(P, Vts, out);
}

// Round 10
// 379.623 us; speedup vs baseline: 2.3611x; 1.0095x over previous
//
#include <hip/hip_runtime.h>
#include <math.h>

// GATLayer fused, round 10 (= round-9 kernel, resubmitted after broker timeout):
// colstat rebuilt for memory-level parallelism — all 24 edge int4 loads issued
// up front (96 VGPR), then compute. (r8 lesson: occupancy 19->42% left colstat
// flat at 76us; the limiter is per-thread outstanding loads, not wave count.)
// Pipeline: wvec -> svec_split (svec + hs1) -> colstat(P,pl) -> combine(t)
//           -> split_wtb -> gemm_v (h1@W -> V*t, split-bf16) -> av (P@V, +elu)

#define B 4
#define N 2048
#define D 768
#define BN_TOT (B * N)          // 8192
#define NSPLIT 256
#define ISPAN (N / NSPLIT)      // 8

constexpr float ALPHA = 0.2f;
constexpr float SCALE = 0.01f;

typedef __attribute__((ext_vector_type(8))) short bf16x8;   // 8 bf16 = 4 VGPR
typedef __attribute__((ext_vector_type(4))) short short4v;
typedef __attribute__((ext_vector_type(4))) float f32x4;

__device__ __forceinline__ float leaky(float x) { return x > 0.f ? x : ALPHA * x; }

// fp32 -> bf16 hi + bf16 lo (truncated hi; residual exact -> ~16-bit mantissa)
__device__ __forceinline__ void split2(float x, short& h, short& l) {
    unsigned bx = __float_as_uint(x);
    h = (short)(bx >> 16);
    float r = x - __uint_as_float(bx & 0xffff0000u);
    l = (short)(__float_as_uint(r) >> 16);
}

__device__ __forceinline__ unsigned short rne_bf16(float x) {
    unsigned bx = __float_as_uint(x);
    bx += 0x7fffu + ((bx >> 16) & 1u);
    return (unsigned short)(bx >> 16);
}
__device__ __forceinline__ float bf16f(unsigned short h) {
    return __uint_as_float(((unsigned)h) << 16);
}

__device__ __forceinline__ void gload16(const void* g, void* l) {
    __builtin_amdgcn_global_load_lds(
        (const __attribute__((address_space(1))) void*)g,
        (__attribute__((address_space(3))) void*)l, 16, 0, 0);
}

// ---------------------------------------------------------------------------
// K0: wv[v][k] = sum_d W[k,d]*vec_v[d];  v = (a,n1,n2,n3) x (lo, hi halves).
// grid 192 x 256 (wave per k)
// ---------------------------------------------------------------------------
__global__ __launch_bounds__(256) void wvec_kernel(
    const float* __restrict__ W, const float* __restrict__ a,
    const float* __restrict__ n1, const float* __restrict__ n2,
    const float* __restrict__ n3, float* __restrict__ wv) {
    const int wave = threadIdx.x >> 6, lane = threadIdx.x & 63;
    const int k = blockIdx.x * 4 + wave;
    const float* wr = W + (size_t)k * D;
    float s[8] = {0.f, 0.f, 0.f, 0.f, 0.f, 0.f, 0.f, 0.f};
    #pragma unroll
    for (int t = 0; t < D / 64; ++t) {
        const int d = lane + t * 64;
        const float w = wr[d];
        s[0] = fmaf(w, a[d],      s[0]);  s[1] = fmaf(w, a[D + d],  s[1]);
        s[2] = fmaf(w, n1[d],     s[2]);  s[3] = fmaf(w, n1[D + d], s[3]);
        s[4] = fmaf(w, n2[d],     s[4]);  s[5] = fmaf(w, n2[D + d], s[5]);
        s[6] = fmaf(w, n3[d],     s[6]);  s[7] = fmaf(w, n3[D + d], s[7]);
    }
    #pragma unroll
    for (int v = 0; v < 8; ++v) {
        float x = s[v];
        #pragma unroll
        for (int off = 32; off; off >>= 1) x += __shfl_xor(x, off);
        if (lane == 0) wv[v * D + k] = x;
    }
}

// ---------------------------------------------------------------------------
// K1: svec[v][row] = h{0|1}[row,:].wv[v]  (float4 loads)  +  h1 -> hs1 split32.
// grid 2048 x 256 (wave per row, 4 rows/block)
// ---------------------------------------------------------------------------
__global__ __launch_bounds__(256) void svec_split_kernel(
    const float* __restrict__ h0, const float* __restrict__ h1,
    const float* __restrict__ wv, float* __restrict__ svec,
    char* __restrict__ hs1) {
    __shared__ float wvs[8 * D];   // 24 KB
    for (int x = threadIdx.x; x < 8 * D; x += 256) wvs[x] = wv[x];
    __syncthreads();
    const int wave = threadIdx.x >> 6, lane = threadIdx.x & 63;
    const int row = blockIdx.x * 4 + wave;
    float s[8] = {0.f, 0.f, 0.f, 0.f, 0.f, 0.f, 0.f, 0.f};
    #pragma unroll
    for (int t = 0; t < 3; ++t) {
        const int k0 = t * 256 + lane * 4;
        const float4 a0 = *(const float4*)&h0[(size_t)row * D + k0];
        const float4 a1 = *(const float4*)&h1[(size_t)row * D + k0];
        #pragma unroll
        for (int v = 0; v < 8; v += 2) {
            const float4 w0 = *(const float4*)&wvs[v * D + k0];
            const float4 w1 = *(const float4*)&wvs[(v + 1) * D + k0];
            s[v]     = fmaf(a0.x, w0.x, fmaf(a0.y, w0.y,
                       fmaf(a0.z, w0.z, fmaf(a0.w, w0.w, s[v]))));
            s[v + 1] = fmaf(a1.x, w1.x, fmaf(a1.y, w1.y,
                       fmaf(a1.z, w1.z, fmaf(a1.w, w1.w, s[v + 1]))));
        }
        // fused split_h1: write this float4 of h1 as split32 hi/lo (8B each)
        short hh[4], ll[4];
        split2(a1.x, hh[0], ll[0]); split2(a1.y, hh[1], ll[1]);
        split2(a1.z, hh[2], ll[2]); split2(a1.w, hh[3], ll[3]);
        char* base = hs1 + (size_t)row * 3072 + (k0 >> 3) * 32 + (k0 & 7) * 2;
        *(short4v*)base        = short4v{hh[0], hh[1], hh[2], hh[3]};
        *(short4v*)(base + 16) = short4v{ll[0], ll[1], ll[2], ll[3]};
    }
    #pragma unroll
    for (int v = 0; v < 8; ++v) {
        float x = s[v];
        #pragma unroll
        for (int off = 32; off; off >>= 1) x += __shfl_xor(x, off);
        if (lane == 0) svec[v * BN_TOT + row] = x;
    }
}

// ---------------------------------------------------------------------------
// K2: P[b,i,j] = bf16(exp(s_ij)); pl partial column sums of the ROUNDED P.
// MLP version: all 24 edge int4 loads (8 i x 3 masks) issued before compute.
// grid (2, 256, 4) x 256, 4 j per thread.
// ---------------------------------------------------------------------------
__global__ __launch_bounds__(256) void colstat_kernel(
    const int* __restrict__ e1, const int* __restrict__ e2,
    const int* __restrict__ e3, const float* __restrict__ svec,
    char* __restrict__ P, float* __restrict__ pl) {
    const int b = blockIdx.z;
    const int i0 = blockIdx.y * ISPAN;
    const int j0 = blockIdx.x * 1024 + threadIdx.x * 4;
    const int bn = b * N;

    // ---- issue ALL edge loads first: 24 outstanding int4 per thread ----
    int4 m1r[ISPAN], m2r[ISPAN], m3r[ISPAN];
    #pragma unroll
    for (int t = 0; t < ISPAN; ++t) {
        const size_t eoff = (size_t)(bn + i0 + t) * N + j0;
        m1r[t] = *(const int4*)&e1[eoff];
        m2r[t] = *(const int4*)&e2[eoff];
        m3r[t] = *(const int4*)&e3[eoff];
    }

    // ---- wave-uniform u-scalars (scalar-cache path) ----
    float ua[ISPAN], u1[ISPAN], u2[ISPAN], u3[ISPAN];
    #pragma unroll
    for (int t = 0; t < ISPAN; ++t) {
        ua[t] = svec[0 * BN_TOT + bn + i0 + t];
        u1[t] = svec[2 * BN_TOT + bn + i0 + t];
        u2[t] = svec[4 * BN_TOT + bn + i0 + t];
        u3[t] = svec[6 * BN_TOT + bn + i0 + t];
    }

    const float4 va = *(const float4*)&svec[1 * BN_TOT + bn + j0];
    const float4 v1 = *(const float4*)&svec[3 * BN_TOT + bn + j0];
    const float4 v2 = *(const float4*)&svec[5 * BN_TOT + bn + j0];
    const float4 v3 = *(const float4*)&svec[7 * BN_TOT + bn + j0];
    const float vaa[4] = {va.x, va.y, va.z, va.w};
    const float v1a[4] = {v1.x, v1.y, v1.z, v1.w};
    const float v2a[4] = {v2.x, v2.y, v2.z, v2.w};
    const float v3a[4] = {v3.x, v3.y, v3.z, v3.w};

    float l[4] = {0.f, 0.f, 0.f, 0.f};
    #pragma unroll
    for (int t = 0; t < ISPAN; ++t) {
        const int m1a[4] = {m1r[t].x, m1r[t].y, m1r[t].z, m1r[t].w};
        const int m2a[4] = {m2r[t].x, m2r[t].y, m2r[t].z, m2r[t].w};
        const int m3a[4] = {m3r[t].x, m3r[t].y, m3r[t].z, m3r[t].w};
        unsigned short pb[4];
        #pragma unroll
        for (int c = 0; c < 4; ++c) {
            float s = leaky(ua[t] + vaa[c]);
            float at = 0.f;
            at += (m1a[c] > 0) ? leaky(u1[t] + v1a[c]) : 0.f;
            at += (m2a[c] > 0) ? leaky(u2[t] + v2a[c]) : 0.f;
            at += (m3a[c] > 0) ? leaky(u3[t] + v3a[c]) : 0.f;
            s = fmaf(SCALE, at, s);
            pb[c] = rne_bf16(__expf(s));
            l[c] += bf16f(pb[c]);    // normalize over exactly what av consumes
        }
        *(short4v*)(P + ((size_t)(bn + i0 + t) * N + j0) * 2) =
            short4v{(short)pb[0], (short)pb[1], (short)pb[2], (short)pb[3]};
    }
    *(float4*)&pl[(size_t)(b * NSPLIT + blockIdx.y) * N + j0] =
        make_float4(l[0], l[1], l[2], l[3]);
}

// ---------------------------------------------------------------------------
// K3: t[b*N+j] = 1 / sum_s pl  (attention = P * t, folded into V)
// ---------------------------------------------------------------------------
__global__ __launch_bounds__(256) void combine_kernel(
    const float* __restrict__ pl, float* __restrict__ tsc) {
    const int idx = blockIdx.x * 256 + threadIdx.x;   // b*N + j
    const int b = idx >> 11, j = idx & (N - 1);
    float sum = 0.f;
    #pragma unroll 8
    for (int s = 0; s < NSPLIT; ++s)
        sum += pl[(size_t)(b * NSPLIT + s) * N + j];
    tsc[idx] = 1.0f / sum;
}

// ---------------------------------------------------------------------------
// K5: W[k][n] -> Wtb[n][k] plain bf16 (RNE). grid 288 x 256
// ---------------------------------------------------------------------------
__global__ __launch_bounds__(256) void split_wtb_kernel(
    const float* __restrict__ W, char* __restrict__ Wtb) {
    const int cidx = blockIdx.x * 256 + threadIdx.x;   // 768*96 = 73728
    const int n = cidx / (D / 8);
    const int k0 = (cidx % (D / 8)) * 8;
    short h[8];
    #pragma unroll
    for (int e = 0; e < 8; ++e) h[e] = (short)rne_bf16(W[(size_t)(k0 + e) * D + n]);
    *(bf16x8*)(Wtb + (size_t)cidx * 16) = bf16x8{h[0],h[1],h[2],h[3],h[4],h[5],h[6],h[7]};
}

// ---------------------------------------------------------------------------
// K6: V = (h1 @ W) * t, written as Vt[b][d][j] split32.
// 64x128 tile (rows x d), BK=64, 4 waves 2x2 (32x64/wave), 2-term MFMA
// (Ah*W + Al*W). LDS 32 KB: Ah 8K | Al 8K | Bw 16K. grid (6, 128) x 256
// ---------------------------------------------------------------------------
__global__ __launch_bounds__(256, 2) void gemm_v(
    const char* __restrict__ hs1, const char* __restrict__ Wtb,
    const float* __restrict__ tsc, char* __restrict__ Vts) {
    __shared__ char lds[32768];
    const int tid = threadIdx.x, wid = tid >> 6, lane = tid & 63;
    const int row0 = blockIdx.y * 64;     // global h1-row (b*N+j)
    const int col0 = blockIdx.x * 128;    // d
    const char* Asrc = hs1 + (size_t)row0 * 3072;
    const char* Bsrc = Wtb + (size_t)col0 * 1536;
    const int wr = wid >> 1, wc = wid & 1;
    const int lrow = lane & 15, kg = lane >> 4;
    f32x4 acc[2][4] = {};

    for (int kt = 0; kt < D / 64; ++kt) {
        __syncthreads();
        #pragma unroll
        for (int s = 0; s < 2; ++s) {      // A: 8 segs x 1KB (hi+lo)
            const int seg = s * 4 + wid;
            const int row = seg * 8 + (lane >> 3);          // 0..63
            const int c = (lane & 7) ^ (row & 7);
            const char* ga = Asrc + (size_t)kt * 256 + (size_t)row * 3072 + c * 32;
            gload16(ga,      lds + seg * 1024);
            gload16(ga + 16, lds + 8192 + seg * 1024);
        }
        #pragma unroll
        for (int s = 0; s < 4; ++s) {      // B: 16 segs x 1KB
            const int seg = s * 4 + wid;
            const int row = seg * 8 + (lane >> 3);          // 0..127
            const int c = (lane & 7) ^ (row & 7);
            gload16(Bsrc + (size_t)kt * 128 + (size_t)row * 1536 + c * 16,
                    lds + 16384 + seg * 1024);
        }
        __syncthreads();
        #pragma unroll
        for (int ks = 0; ks < 2; ++ks) {
            bf16x8 ah[2], al[2], bw[4];
            #pragma unroll
            for (int m = 0; m < 2; ++m) {
                const int r = wr * 32 + m * 16 + lrow;
                const int c = (ks * 4 + kg) ^ (r & 7);
                ah[m] = *(const bf16x8*)(lds + r * 128 + c * 16);
                al[m] = *(const bf16x8*)(lds + 8192 + r * 128 + c * 16);
            }
            #pragma unroll
            for (int n = 0; n < 4; ++n) {
                const int r = wc * 64 + n * 16 + lrow;
                const int c = (ks * 4 + kg) ^ (r & 7);
                bw[n] = *(const bf16x8*)(lds + 16384 + r * 128 + c * 16);
            }
            #pragma unroll
            for (int m = 0; m < 2; ++m)
                #pragma unroll
                for (int n = 0; n < 4; ++n) {
                    acc[m][n] = __builtin_amdgcn_mfma_f32_16x16x32_bf16(ah[m], bw[n], acc[m][n], 0, 0, 0);
                    acc[m][n] = __builtin_amdgcn_mfma_f32_16x16x32_bf16(al[m], bw[n], acc[m][n], 0, 0, 0);
                }
        }
    }
    #pragma unroll
    for (int m = 0; m < 2; ++m)
        #pragma unroll
        for (int n = 0; n < 4; ++n) {
            const int rowb = row0 + wr * 32 + m * 16 + kg * 4;   // b*N + j
            const int col = col0 + wc * 64 + n * 16 + lrow;      // d
            const int bq = rowb >> 11, j = rowb & (N - 1);
            short h4[4], l4[4];
            #pragma unroll
            for (int r = 0; r < 4; ++r) {
                const float x = acc[m][n][r] * tsc[bq * N + j + r];
                split2(x, h4[r], l4[r]);
            }
            char* base = Vts + ((size_t)(bq * D + col)) * 8192 + (j >> 3) * 32 + (j & 7) * 2;
            *(short4v*)base        = short4v{h4[0], h4[1], h4[2], h4[3]};
            *(short4v*)(base + 16) = short4v{l4[0], l4[1], l4[2], l4[3]};
        }
}

// ---------------------------------------------------------------------------
// K7: out = elu(P @ V).  A = P plain bf16, B = V split (2 MFMA: P*Vh + P*Vl).
// 64x128 tile (i x d), BK=64, LDS 40 KB: Ap 8K | Bh 16K | Bl 16K.
// grid (6, 32, 4) x 256
// ---------------------------------------------------------------------------
__global__ __launch_bounds__(256, 2) void av_kernel(
    const char* __restrict__ P, const char* __restrict__ Vts,
    float* __restrict__ out) {
    __shared__ char lds[40960];
    const int tid = threadIdx.x, wid = tid >> 6, lane = tid & 63;
    const int b = blockIdx.z;
    const int i0 = blockIdx.y * 64, d0 = blockIdx.x * 128;
    const char* Asrc = P + ((size_t)(b * N + i0)) * 4096;     // P row = 4 KB
    const char* Bsrc = Vts + ((size_t)(b * D + d0)) * 8192;   // Vt row = 8 KB
    const int wr = wid >> 1, wc = wid & 1;
    const int lrow = lane & 15, kg = lane >> 4;
    f32x4 acc[2][4] = {};

    for (int kt = 0; kt < N / 64; ++kt) {
        __syncthreads();
        #pragma unroll
        for (int s = 0; s < 2; ++s) {      // A: 8 segs
            const int seg = s * 4 + wid;
            const int row = seg * 8 + (lane >> 3);          // 0..63 (i-local)
            const int c = (lane & 7) ^ (row & 7);
            gload16(Asrc + (size_t)kt * 128 + (size_t)row * 4096 + c * 16,
                    lds + seg * 1024);
        }
        #pragma unroll
        for (int s = 0; s < 4; ++s) {      // B: 16 segs (hi+lo)
            const int seg = s * 4 + wid;
            const int row = seg * 8 + (lane >> 3);          // 0..127 (d-local)
            const int c = (lane & 7) ^ (row & 7);
            const char* gb = Bsrc + (size_t)kt * 256 + (size_t)row * 8192 + c * 32;
            gload16(gb,      lds + 8192 + seg * 1024);
            gload16(gb + 16, lds + 24576 + seg * 1024);
        }
        __syncthreads();
        #pragma unroll
        for (int ks = 0; ks < 2; ++ks) {
            bf16x8 ap[2], bh[4], bl[4];
            #pragma unroll
            for (int m = 0; m < 2; ++m) {
                const int r = wr * 32 + m * 16 + lrow;
                const int c = (ks * 4 + kg) ^ (r & 7);
                ap[m] = *(const bf16x8*)(lds + r * 128 + c * 16);
            }
            #pragma unroll
            for (int n = 0; n < 4; ++n) {
                const int r = wc * 64 + n * 16 + lrow;
                const int c = (ks * 4 + kg) ^ (r & 7);
                bh[n] = *(const bf16x8*)(lds + 8192 + r * 128 + c * 16);
                bl[n] = *(const bf16x8*)(lds + 24576 + r * 128 + c * 16);
            }
            #pragma unroll
            for (int m = 0; m < 2; ++m)
                #pragma unroll
                for (int n = 0; n < 4; ++n) {
                    acc[m][n] = __builtin_amdgcn_mfma_f32_16x16x32_bf16(ap[m], bh[n], acc[m][n], 0, 0, 0);
                    acc[m][n] = __builtin_amdgcn_mfma_f32_16x16x32_bf16(ap[m], bl[n], acc[m][n], 0, 0, 0);
                }
        }
    }
    #pragma unroll
    for (int m = 0; m < 2; ++m)
        #pragma unroll
        for (int n = 0; n < 4; ++n) {
            const int rowi = i0 + wr * 32 + m * 16 + kg * 4;
            const int col = d0 + wc * 64 + n * 16 + lrow;
            #pragma unroll
            for (int r = 0; r < 4; ++r) {
                const float x = acc[m][n][r];
                out[((size_t)(b * N + rowi + r)) * D + col] = x > 0.f ? x : expm1f(x);
            }
        }
}

// ---------------------------------------------------------------------------
extern "C" void kernel_launch(void* const* d_in, const int* in_sizes, int n_in,
                              void* d_out, int out_size, void* d_ws, size_t ws_size,
                              hipStream_t stream) {
    const float* h0  = (const float*)d_in[0];
    const float* h1  = (const float*)d_in[1];
    const float* nl1 = (const float*)d_in[2];
    const int*   e1  = (const int*)d_in[3];
    const float* nl2 = (const float*)d_in[4];
    const int*   e2  = (const int*)d_in[5];
    const float* nl3 = (const float*)d_in[6];
    const int*   e3  = (const int*)d_in[7];
    const float* W   = (const float*)d_in[8];
    const float* a   = (const float*)d_in[9];
    float* out = (float*)d_out;

    // workspace layout (~94 MB)
    char* ws = (char*)d_ws;
    char*  P    = ws;                          // 33,554,432  B*N*N bf16
    char*  hs1  = ws + 33554432;               // 25,165,824  split32
    char*  Wtb  = ws + 58720256;               //  1,179,648  bf16 [n][k]
    char*  Vts  = ws + 59899904;               // 25,165,824  split32 [b][d][j]
    float* wv   = (float*)(ws + 85065728);     //     24,576  8 x 768
    float* svec = (float*)(ws + 85090304);     //    262,144  8 x 8192
    float* pl   = (float*)(ws + 85352448);     //  8,388,608  256 x 8192
    float* tsc  = (float*)(ws + 93741056);     //     32,768  8192

    wvec_kernel<<<192, 256, 0, stream>>>(W, a, nl1, nl2, nl3, wv);
    svec_split_kernel<<<2048, 256, 0, stream>>>(h0, h1, wv, svec, hs1);
    colstat_kernel<<<dim3(2, NSPLIT, B), 256, 0, stream>>>(e1, e2, e3, svec, P, pl);
    combine_kernel<<<BN_TOT / 256, 256, 0, stream>>>(pl, tsc);
    split_wtb_kernel<<<288, 256, 0, stream>>>(W, Wtb);
    gemm_v<<<dim3(6, 128), 256, 0, stream>>>(hs1, Wtb, tsc, Vts);
    av_kernel<<<dim3(6, 32, 4), 256, 0, stream>>>(P, Vts, out);
}

// Round 12
// 344.073 us; speedup vs baseline: 2.6050x; 1.1033x over previous
//
#include <hip/hip_runtime.h>
#include <math.h>

// GATLayer fused, round 12 (= round-11 kernel, resubmitted after broker timeout):
// error-budget-consistent precision — P is already bf16 (0.4% rel, dominates),
// so split-precision V / h1 wasted 2x MFMA FLOPs below the error floor.
// Both GEMMs single-term plain bf16.
// Pipeline: wvec -> svec_split (svec + h1 bf16) -> colstat(P,pl) -> combine(t)
//           -> split_wtb -> gemm_v (h1b@Wb -> V*t bf16) -> av (P@V, +elu)

#define B 4
#define N 2048
#define D 768
#define BN_TOT (B * N)          // 8192
#define NSPLIT 256
#define ISPAN (N / NSPLIT)      // 8

constexpr float ALPHA = 0.2f;
constexpr float SCALE = 0.01f;

typedef __attribute__((ext_vector_type(8))) short bf16x8;   // 8 bf16 = 4 VGPR
typedef __attribute__((ext_vector_type(4))) short short4v;
typedef __attribute__((ext_vector_type(4))) float f32x4;

__device__ __forceinline__ float leaky(float x) { return x > 0.f ? x : ALPHA * x; }

__device__ __forceinline__ unsigned short rne_bf16(float x) {
    unsigned bx = __float_as_uint(x);
    bx += 0x7fffu + ((bx >> 16) & 1u);
    return (unsigned short)(bx >> 16);
}
__device__ __forceinline__ float bf16f(unsigned short h) {
    return __uint_as_float(((unsigned)h) << 16);
}

__device__ __forceinline__ void gload16(const void* g, void* l) {
    __builtin_amdgcn_global_load_lds(
        (const __attribute__((address_space(1))) void*)g,
        (__attribute__((address_space(3))) void*)l, 16, 0, 0);
}

// ---------------------------------------------------------------------------
// K0: wv[v][k] = sum_d W[k,d]*vec_v[d];  v = (a,n1,n2,n3) x (lo, hi halves).
// grid 192 x 256 (wave per k)
// ---------------------------------------------------------------------------
__global__ __launch_bounds__(256) void wvec_kernel(
    const float* __restrict__ W, const float* __restrict__ a,
    const float* __restrict__ n1, const float* __restrict__ n2,
    const float* __restrict__ n3, float* __restrict__ wv) {
    const int wave = threadIdx.x >> 6, lane = threadIdx.x & 63;
    const int k = blockIdx.x * 4 + wave;
    const float* wr = W + (size_t)k * D;
    float s[8] = {0.f, 0.f, 0.f, 0.f, 0.f, 0.f, 0.f, 0.f};
    #pragma unroll
    for (int t = 0; t < D / 64; ++t) {
        const int d = lane + t * 64;
        const float w = wr[d];
        s[0] = fmaf(w, a[d],      s[0]);  s[1] = fmaf(w, a[D + d],  s[1]);
        s[2] = fmaf(w, n1[d],     s[2]);  s[3] = fmaf(w, n1[D + d], s[3]);
        s[4] = fmaf(w, n2[d],     s[4]);  s[5] = fmaf(w, n2[D + d], s[5]);
        s[6] = fmaf(w, n3[d],     s[6]);  s[7] = fmaf(w, n3[D + d], s[7]);
    }
    #pragma unroll
    for (int v = 0; v < 8; ++v) {
        float x = s[v];
        #pragma unroll
        for (int off = 32; off; off >>= 1) x += __shfl_xor(x, off);
        if (lane == 0) wv[v * D + k] = x;
    }
}

// ---------------------------------------------------------------------------
// K1: svec[v][row] = h{0|1}[row,:].wv[v]  (float4 loads)  +  h1 -> bf16 (RNE).
// grid 2048 x 256 (wave per row, 4 rows/block)
// ---------------------------------------------------------------------------
__global__ __launch_bounds__(256) void svec_split_kernel(
    const float* __restrict__ h0, const float* __restrict__ h1,
    const float* __restrict__ wv, float* __restrict__ svec,
    char* __restrict__ hs1) {
    __shared__ float wvs[8 * D];   // 24 KB
    for (int x = threadIdx.x; x < 8 * D; x += 256) wvs[x] = wv[x];
    __syncthreads();
    const int wave = threadIdx.x >> 6, lane = threadIdx.x & 63;
    const int row = blockIdx.x * 4 + wave;
    float s[8] = {0.f, 0.f, 0.f, 0.f, 0.f, 0.f, 0.f, 0.f};
    #pragma unroll
    for (int t = 0; t < 3; ++t) {
        const int k0 = t * 256 + lane * 4;
        const float4 a0 = *(const float4*)&h0[(size_t)row * D + k0];
        const float4 a1 = *(const float4*)&h1[(size_t)row * D + k0];
        #pragma unroll
        for (int v = 0; v < 8; v += 2) {
            const float4 w0 = *(const float4*)&wvs[v * D + k0];
            const float4 w1 = *(const float4*)&wvs[(v + 1) * D + k0];
            s[v]     = fmaf(a0.x, w0.x, fmaf(a0.y, w0.y,
                       fmaf(a0.z, w0.z, fmaf(a0.w, w0.w, s[v]))));
            s[v + 1] = fmaf(a1.x, w1.x, fmaf(a1.y, w1.y,
                       fmaf(a1.z, w1.z, fmaf(a1.w, w1.w, s[v + 1]))));
        }
        // h1 -> plain bf16 row (RNE), 8 B per lane per iter
        short hh[4];
        hh[0] = (short)rne_bf16(a1.x); hh[1] = (short)rne_bf16(a1.y);
        hh[2] = (short)rne_bf16(a1.z); hh[3] = (short)rne_bf16(a1.w);
        *(short4v*)(hs1 + (size_t)row * 1536 + k0 * 2) =
            short4v{hh[0], hh[1], hh[2], hh[3]};
    }
    #pragma unroll
    for (int v = 0; v < 8; ++v) {
        float x = s[v];
        #pragma unroll
        for (int off = 32; off; off >>= 1) x += __shfl_xor(x, off);
        if (lane == 0) svec[v * BN_TOT + row] = x;
    }
}

// ---------------------------------------------------------------------------
// K2: P[b,i,j] = bf16(exp(s_ij)); pl partial column sums of the ROUNDED P.
// grid (2, 256, 4) x 256, 4 j per thread.  (unchanged control)
// ---------------------------------------------------------------------------
__global__ __launch_bounds__(256) void colstat_kernel(
    const int* __restrict__ e1, const int* __restrict__ e2,
    const int* __restrict__ e3, const float* __restrict__ svec,
    char* __restrict__ P, float* __restrict__ pl) {
    const int b = blockIdx.z;
    const int i0 = blockIdx.y * ISPAN;
    const int j0 = blockIdx.x * 1024 + threadIdx.x * 4;
    const int bn = b * N;

    int4 m1r[ISPAN], m2r[ISPAN], m3r[ISPAN];
    #pragma unroll
    for (int t = 0; t < ISPAN; ++t) {
        const size_t eoff = (size_t)(bn + i0 + t) * N + j0;
        m1r[t] = *(const int4*)&e1[eoff];
        m2r[t] = *(const int4*)&e2[eoff];
        m3r[t] = *(const int4*)&e3[eoff];
    }
    float ua[ISPAN], u1[ISPAN], u2[ISPAN], u3[ISPAN];
    #pragma unroll
    for (int t = 0; t < ISPAN; ++t) {
        ua[t] = svec[0 * BN_TOT + bn + i0 + t];
        u1[t] = svec[2 * BN_TOT + bn + i0 + t];
        u2[t] = svec[4 * BN_TOT + bn + i0 + t];
        u3[t] = svec[6 * BN_TOT + bn + i0 + t];
    }
    const float4 va = *(const float4*)&svec[1 * BN_TOT + bn + j0];
    const float4 v1 = *(const float4*)&svec[3 * BN_TOT + bn + j0];
    const float4 v2 = *(const float4*)&svec[5 * BN_TOT + bn + j0];
    const float4 v3 = *(const float4*)&svec[7 * BN_TOT + bn + j0];
    const float vaa[4] = {va.x, va.y, va.z, va.w};
    const float v1a[4] = {v1.x, v1.y, v1.z, v1.w};
    const float v2a[4] = {v2.x, v2.y, v2.z, v2.w};
    const float v3a[4] = {v3.x, v3.y, v3.z, v3.w};

    float l[4] = {0.f, 0.f, 0.f, 0.f};
    #pragma unroll
    for (int t = 0; t < ISPAN; ++t) {
        const int m1a[4] = {m1r[t].x, m1r[t].y, m1r[t].z, m1r[t].w};
        const int m2a[4] = {m2r[t].x, m2r[t].y, m2r[t].z, m2r[t].w};
        const int m3a[4] = {m3r[t].x, m3r[t].y, m3r[t].z, m3r[t].w};
        unsigned short pb[4];
        #pragma unroll
        for (int c = 0; c < 4; ++c) {
            float s = leaky(ua[t] + vaa[c]);
            float at = 0.f;
            at += (m1a[c] > 0) ? leaky(u1[t] + v1a[c]) : 0.f;
            at += (m2a[c] > 0) ? leaky(u2[t] + v2a[c]) : 0.f;
            at += (m3a[c] > 0) ? leaky(u3[t] + v3a[c]) : 0.f;
            s = fmaf(SCALE, at, s);
            pb[c] = rne_bf16(__expf(s));
            l[c] += bf16f(pb[c]);    // normalize over exactly what av consumes
        }
        *(short4v*)(P + ((size_t)(bn + i0 + t) * N + j0) * 2) =
            short4v{(short)pb[0], (short)pb[1], (short)pb[2], (short)pb[3]};
    }
    *(float4*)&pl[(size_t)(b * NSPLIT + blockIdx.y) * N + j0] =
        make_float4(l[0], l[1], l[2], l[3]);
}

// ---------------------------------------------------------------------------
// K3: t[b*N+j] = 1 / sum_s pl  (attention = P * t, folded into V)
// ---------------------------------------------------------------------------
__global__ __launch_bounds__(256) void combine_kernel(
    const float* __restrict__ pl, float* __restrict__ tsc) {
    const int idx = blockIdx.x * 256 + threadIdx.x;   // b*N + j
    const int b = idx >> 11, j = idx & (N - 1);
    float sum = 0.f;
    #pragma unroll 8
    for (int s = 0; s < NSPLIT; ++s)
        sum += pl[(size_t)(b * NSPLIT + s) * N + j];
    tsc[idx] = 1.0f / sum;
}

// ---------------------------------------------------------------------------
// K5: W[k][n] -> Wtb[n][k] plain bf16 (RNE). grid 288 x 256
// ---------------------------------------------------------------------------
__global__ __launch_bounds__(256) void split_wtb_kernel(
    const float* __restrict__ W, char* __restrict__ Wtb) {
    const int cidx = blockIdx.x * 256 + threadIdx.x;   // 768*96 = 73728
    const int n = cidx / (D / 8);
    const int k0 = (cidx % (D / 8)) * 8;
    short h[8];
    #pragma unroll
    for (int e = 0; e < 8; ++e) h[e] = (short)rne_bf16(W[(size_t)(k0 + e) * D + n]);
    *(bf16x8*)(Wtb + (size_t)cidx * 16) = bf16x8{h[0],h[1],h[2],h[3],h[4],h[5],h[6],h[7]};
}

// ---------------------------------------------------------------------------
// K6: V = (h1 @ W) * t -> Vtb[b][d][j] plain bf16. Single-term MFMA.
// 64x128 tile (rows x d), BK=64, 4 waves 2x2 (32x64/wave).
// LDS 24 KB: A 8K | B 16K. grid (6, 128) x 256
// ---------------------------------------------------------------------------
__global__ __launch_bounds__(256, 2) void gemm_v(
    const char* __restrict__ hs1, const char* __restrict__ Wtb,
    const float* __restrict__ tsc, char* __restrict__ Vtb) {
    __shared__ char lds[24576];
    const int tid = threadIdx.x, wid = tid >> 6, lane = tid & 63;
    const int row0 = blockIdx.y * 64;     // global h1-row (b*N+j)
    const int col0 = blockIdx.x * 128;    // d
    const char* Asrc = hs1 + (size_t)row0 * 1536;
    const char* Bsrc = Wtb + (size_t)col0 * 1536;
    const int wr = wid >> 1, wc = wid & 1;
    const int lrow = lane & 15, kg = lane >> 4;
    f32x4 acc[2][4] = {};

    for (int kt = 0; kt < D / 64; ++kt) {
        __syncthreads();
        #pragma unroll
        for (int s = 0; s < 2; ++s) {      // A: 8 segs x 1KB
            const int seg = s * 4 + wid;
            const int row = seg * 8 + (lane >> 3);          // 0..63
            const int c = (lane & 7) ^ (row & 7);
            gload16(Asrc + (size_t)kt * 128 + (size_t)row * 1536 + c * 16,
                    lds + seg * 1024);
        }
        #pragma unroll
        for (int s = 0; s < 4; ++s) {      // B: 16 segs x 1KB
            const int seg = s * 4 + wid;
            const int row = seg * 8 + (lane >> 3);          // 0..127
            const int c = (lane & 7) ^ (row & 7);
            gload16(Bsrc + (size_t)kt * 128 + (size_t)row * 1536 + c * 16,
                    lds + 8192 + seg * 1024);
        }
        __syncthreads();
        #pragma unroll
        for (int ks = 0; ks < 2; ++ks) {
            bf16x8 ah[2], bw[4];
            #pragma unroll
            for (int m = 0; m < 2; ++m) {
                const int r = wr * 32 + m * 16 + lrow;
                const int c = (ks * 4 + kg) ^ (r & 7);
                ah[m] = *(const bf16x8*)(lds + r * 128 + c * 16);
            }
            #pragma unroll
            for (int n = 0; n < 4; ++n) {
                const int r = wc * 64 + n * 16 + lrow;
                const int c = (ks * 4 + kg) ^ (r & 7);
                bw[n] = *(const bf16x8*)(lds + 8192 + r * 128 + c * 16);
            }
            #pragma unroll
            for (int m = 0; m < 2; ++m)
                #pragma unroll
                for (int n = 0; n < 4; ++n)
                    acc[m][n] = __builtin_amdgcn_mfma_f32_16x16x32_bf16(ah[m], bw[n], acc[m][n], 0, 0, 0);
        }
    }
    #pragma unroll
    for (int m = 0; m < 2; ++m)
        #pragma unroll
        for (int n = 0; n < 4; ++n) {
            const int rowb = row0 + wr * 32 + m * 16 + kg * 4;   // b*N + j
            const int col = col0 + wc * 64 + n * 16 + lrow;      // d
            const int bq = rowb >> 11, j = rowb & (N - 1);
            short h4[4];
            #pragma unroll
            for (int r = 0; r < 4; ++r)
                h4[r] = (short)rne_bf16(acc[m][n][r] * tsc[bq * N + j + r]);
            *(short4v*)(Vtb + ((size_t)(bq * D + col)) * 4096 + j * 2) =
                short4v{h4[0], h4[1], h4[2], h4[3]};
        }
}

// ---------------------------------------------------------------------------
// K7: out = elu(P @ V).  Both operands plain bf16, single-term MFMA.
// 64x128 tile (i x d), BK=64, LDS 24 KB: A 8K | B 16K. grid (6, 32, 4) x 256
// ---------------------------------------------------------------------------
__global__ __launch_bounds__(256, 2) void av_kernel(
    const char* __restrict__ P, const char* __restrict__ Vtb,
    float* __restrict__ out) {
    __shared__ char lds[24576];
    const int tid = threadIdx.x, wid = tid >> 6, lane = tid & 63;
    const int b = blockIdx.z;
    const int i0 = blockIdx.y * 64, d0 = blockIdx.x * 128;
    const char* Asrc = P + ((size_t)(b * N + i0)) * 4096;     // P row = 4 KB
    const char* Bsrc = Vtb + ((size_t)(b * D + d0)) * 4096;   // Vt row = 4 KB
    const int wr = wid >> 1, wc = wid & 1;
    const int lrow = lane & 15, kg = lane >> 4;
    f32x4 acc[2][4] = {};

    for (int kt = 0; kt < N / 64; ++kt) {
        __syncthreads();
        #pragma unroll
        for (int s = 0; s < 2; ++s) {      // A: 8 segs
            const int seg = s * 4 + wid;
            const int row = seg * 8 + (lane >> 3);          // 0..63 (i-local)
            const int c = (lane & 7) ^ (row & 7);
            gload16(Asrc + (size_t)kt * 128 + (size_t)row * 4096 + c * 16,
                    lds + seg * 1024);
        }
        #pragma unroll
        for (int s = 0; s < 4; ++s) {      // B: 16 segs
            const int seg = s * 4 + wid;
            const int row = seg * 8 + (lane >> 3);          // 0..127 (d-local)
            const int c = (lane & 7) ^ (row & 7);
            gload16(Bsrc + (size_t)kt * 128 + (size_t)row * 4096 + c * 16,
                    lds + 8192 + seg * 1024);
        }
        __syncthreads();
        #pragma unroll
        for (int ks = 0; ks < 2; ++ks) {
            bf16x8 ap[2], bv[4];
            #pragma unroll
            for (int m = 0; m < 2; ++m) {
                const int r = wr * 32 + m * 16 + lrow;
                const int c = (ks * 4 + kg) ^ (r & 7);
                ap[m] = *(const bf16x8*)(lds + r * 128 + c * 16);
            }
            #pragma unroll
            for (int n = 0; n < 4; ++n) {
                const int r = wc * 64 + n * 16 + lrow;
                const int c = (ks * 4 + kg) ^ (r & 7);
                bv[n] = *(const bf16x8*)(lds + 8192 + r * 128 + c * 16);
            }
            #pragma unroll
            for (int m = 0; m < 2; ++m)
                #pragma unroll
                for (int n = 0; n < 4; ++n)
                    acc[m][n] = __builtin_amdgcn_mfma_f32_16x16x32_bf16(ap[m], bv[n], acc[m][n], 0, 0, 0);
        }
    }
    #pragma unroll
    for (int m = 0; m < 2; ++m)
        #pragma unroll
        for (int n = 0; n < 4; ++n) {
            const int rowi = i0 + wr * 32 + m * 16 + kg * 4;
            const int col = d0 + wc * 64 + n * 16 + lrow;
            #pragma unroll
            for (int r = 0; r < 4; ++r) {
                const float x = acc[m][n][r];
                out[((size_t)(b * N + rowi + r)) * D + col] = x > 0.f ? x : expm1f(x);
            }
        }
}

// ---------------------------------------------------------------------------
extern "C" void kernel_launch(void* const* d_in, const int* in_sizes, int n_in,
                              void* d_out, int out_size, void* d_ws, size_t ws_size,
                              hipStream_t stream) {
    const float* h0  = (const float*)d_in[0];
    const float* h1  = (const float*)d_in[1];
    const float* nl1 = (const float*)d_in[2];
    const int*   e1  = (const int*)d_in[3];
    const float* nl2 = (const float*)d_in[4];
    const int*   e2  = (const int*)d_in[5];
    const float* nl3 = (const float*)d_in[6];
    const int*   e3  = (const int*)d_in[7];
    const float* W   = (const float*)d_in[8];
    const float* a   = (const float*)d_in[9];
    float* out = (float*)d_out;

    // workspace layout (~68.6 MB)
    char* ws = (char*)d_ws;
    char*  P    = ws;                          // 33,554,432  B*N*N bf16
    char*  hs1  = ws + 33554432;               // 12,582,912  h1 bf16
    char*  Wtb  = ws + 46137344;               //  1,179,648  bf16 [n][k]
    char*  Vtb  = ws + 47316992;               // 12,582,912  bf16 [b][d][j]
    float* wv   = (float*)(ws + 59899904);     //     24,576  8 x 768
    float* svec = (float*)(ws + 59924480);     //    262,144  8 x 8192
    float* pl   = (float*)(ws + 60186624);     //  8,388,608  256 x 8192
    float* tsc  = (float*)(ws + 68575232);     //     32,768  8192

    wvec_kernel<<<192, 256, 0, stream>>>(W, a, nl1, nl2, nl3, wv);
    svec_split_kernel<<<2048, 256, 0, stream>>>(h0, h1, wv, svec, hs1);
    colstat_kernel<<<dim3(2, NSPLIT, B), 256, 0, stream>>>(e1, e2, e3, svec, P, pl);
    combine_kernel<<<BN_TOT / 256, 256, 0, stream>>>(pl, tsc);
    split_wtb_kernel<<<288, 256, 0, stream>>>(W, Wtb);
    gemm_v<<<dim3(6, 128), 256, 0, stream>>>(hs1, Wtb, tsc, Vtb);
    av_kernel<<<dim3(6, 32, 4), 256, 0, stream>>>(P, Vtb, out);
}